// Round 1
// baseline (112.881 us; speedup 1.0000x reference)
//
#include <hip/hip_runtime.h>

#define LRELU(v) ((v) >= 0.f ? (v) : 0.2f*(v))

// ---------------- Kernel A: conv stack + f = [hidden(576), |sum(ro)-E|] ----
__global__ __launch_bounds__(256) void convf_kernel(
    const float* __restrict__ readout,   // (512,1,9,9)
    const float* __restrict__ energy,    // (512)
    const float* __restrict__ w1,        // (32,1,4,4)
    const float* __restrict__ w2,        // (64,32,4,4)
    float* __restrict__ f_ws)            // (512,577)
{
    const int n = blockIdx.x;
    const int t = threadIdx.x;
    __shared__ float ro[81];
    __shared__ float w1s[512];
    __shared__ float h1[1152];   // [ic(32)][pos(36)]

    if (t < 81) ro[t] = readout[n*81 + t];
    w1s[t] = w1[t];
    w1s[t+256] = w1[t+256];
    __syncthreads();

    // reco_energy on wave 0
    if (t < 64) {
        float s = ro[t];
        if (t < 17) s += ro[t + 64];
        #pragma unroll
        for (int m = 32; m; m >>= 1) s += __shfl_down(s, m);
        if (t == 0) f_ws[n*577 + 576] = fabsf(s - energy[n]);
    }

    // conv1: 32 x 6 x 6
    for (int idx = t; idx < 1152; idx += 256) {
        const int oc = idx / 36, pos = idx % 36;
        const int y = pos / 6, x = pos % 6;
        const float* wp = &w1s[oc*16];
        float a = 0.f;
        #pragma unroll
        for (int ky = 0; ky < 4; ky++)
            #pragma unroll
            for (int kx = 0; kx < 4; kx++)
                a += wp[ky*4 + kx] * ro[(y+ky)*9 + (x+kx)];
        h1[idx] = LRELU(a);
    }
    __syncthreads();

    // conv2: 64 x 3 x 3, 4 output channels per thread (144 active threads)
    if (t < 144) {
        const int ocq = t / 9, pos = t % 9;
        const int y = pos / 3, x = pos % 3;
        const int ocb = ocq * 4;
        float a0 = 0.f, a1 = 0.f, a2 = 0.f, a3 = 0.f;
        for (int ic = 0; ic < 32; ic++) {
            #pragma unroll
            for (int ky = 0; ky < 4; ky++) {
                const int hb = ic*36 + (y+ky)*6 + x;
                const float h0 = h1[hb], hA = h1[hb+1], hB = h1[hb+2], hC = h1[hb+3];
                const float4* w4 = (const float4*)&w2[ocb*512 + ic*16 + ky*4];
                float4 wa = w4[0];
                float4 wb = w4[128];
                float4 wc = w4[256];
                float4 wd = w4[384];
                a0 += wa.x*h0 + wa.y*hA + wa.z*hB + wa.w*hC;
                a1 += wb.x*h0 + wb.y*hA + wb.z*hB + wb.w*hC;
                a2 += wc.x*h0 + wc.y*hA + wc.z*hB + wc.w*hC;
                a3 += wd.x*h0 + wd.y*hA + wd.z*hB + wd.w*hC;
            }
        }
        float* fo = &f_ws[n*577];
        fo[(ocb+0)*9 + pos] = LRELU(a0);
        fo[(ocb+1)*9 + pos] = LRELU(a1);
        fo[(ocb+2)*9 + pos] = LRELU(a2);
        fo[(ocb+3)*9 + pos] = LRELU(a3);
    }
}

// ---------------- Kernel B: M = F(512x577) @ T(577x512) -------------------
__global__ __launch_bounds__(256) void mgemm_kernel(
    const float* __restrict__ F,
    const float* __restrict__ T,
    float* __restrict__ M)
{
    const int rb = blockIdx.x >> 3;    // 64 row tiles of 8
    const int cb = blockIdx.x & 7;     // 8 col tiles of 64
    const int t = threadIdx.x;
    __shared__ float Fs[8*577];
    const int r0 = rb*8, c0 = cb*64;
    for (int r = 0; r < 8; r++)
        for (int a = t; a < 577; a += 256)
            Fs[r*577 + a] = F[(r0+r)*577 + a];
    __syncthreads();

    const int col = c0 + (t & 63);
    const int rg  = (t >> 6) * 2;      // wave-uniform
    const float* f0 = &Fs[rg*577];
    const float* f1 = &Fs[(rg+1)*577];
    float a0 = 0.f, a1 = 0.f;
    int a = 0;
    for (; a + 4 <= 577; a += 4) {
        float t0 = T[(a+0)*512 + col];
        float t1 = T[(a+1)*512 + col];
        float t2 = T[(a+2)*512 + col];
        float t3 = T[(a+3)*512 + col];
        a0 += f0[a]*t0 + f0[a+1]*t1 + f0[a+2]*t2 + f0[a+3]*t3;
        a1 += f1[a]*t0 + f1[a+1]*t1 + f1[a+2]*t2 + f1[a+3]*t3;
    }
    { // tail (a == 576)
        float tv = T[576*512 + col];
        a0 += f0[576]*tv;
        a1 += f1[576]*tv;
    }
    M[(r0+rg+0)*512 + col] = a0;
    M[(r0+rg+1)*512 + col] = a1;
}

// ---------------- Kernel C: o_part[isp][j][b] = sum_i exp(-L1) ------------
// grid 512: jt = bid>>4 (16 j's each), isp = bid&15 (32 i's each)
__global__ __launch_bounds__(256) void pairwise_kernel(
    const float* __restrict__ M,       // (512,512)
    float* __restrict__ o_part)        // (16,512,32)
{
    const int jt  = blockIdx.x >> 4;
    const int isp = blockIdx.x & 15;
    const int t = threadIdx.x;
    const int b = t & 31, jl = t >> 5;
    const int j0 = jt * 16;
    __shared__ float mi[16*572];       // padded: float off = x + ((x>>5)<<2)

    float m0[16], m1[16];
    {
        const float4* p0 = (const float4*)&M[(j0+jl  )*512 + b*16];
        const float4* p1 = (const float4*)&M[(j0+jl+8)*512 + b*16];
        #pragma unroll
        for (int q = 0; q < 4; q++) {
            float4 v = p0[q];
            m0[4*q+0]=v.x; m0[4*q+1]=v.y; m0[4*q+2]=v.z; m0[4*q+3]=v.w;
            float4 w = p1[q];
            m1[4*q+0]=w.x; m1[4*q+1]=w.y; m1[4*q+2]=w.z; m1[4*q+3]=w.w;
        }
    }

    float acc0 = 0.f, acc1 = 0.f;
    const int lbase = b*16 + ((b>>1)<<2);

    for (int chunk = 0; chunk < 2; chunk++) {
        const int i0 = isp*32 + chunk*16;
        #pragma unroll
        for (int k = 0; k < 8; k++) {
            const int q = k*256 + t;       // 0..2047
            const int r = q >> 7;
            const int x = (q & 127) * 4;
            float4 v = *(const float4*)&M[(i0+r)*512 + x];
            *(float4*)&mi[r*572 + x + ((x>>5)<<2)] = v;
        }
        __syncthreads();
        #pragma unroll 4
        for (int r = 0; r < 16; r++) {
            const float4* q4 = (const float4*)&mi[r*572 + lbase];
            float s0 = 0.f, s1 = 0.f;
            #pragma unroll
            for (int q = 0; q < 4; q++) {
                float4 v = q4[q];
                s0 += fabsf(v.x - m0[4*q+0]) + fabsf(v.y - m0[4*q+1])
                    + fabsf(v.z - m0[4*q+2]) + fabsf(v.w - m0[4*q+3]);
                s1 += fabsf(v.x - m1[4*q+0]) + fabsf(v.y - m1[4*q+1])
                    + fabsf(v.z - m1[4*q+2]) + fabsf(v.w - m1[4*q+3]);
            }
            acc0 += __expf(-s0);
            acc1 += __expf(-s1);
        }
        __syncthreads();
    }
    o_part[isp*16384 + (j0+jl  )*32 + b] = acc0;
    o_part[isp*16384 + (j0+jl+8)*32 + b] = acc1;
}

// ---------------- Kernel D: MLP head, one wave per sample -----------------
__global__ __launch_bounds__(256) void mlp_kernel(
    const float* __restrict__ f,       // (512,577)
    const float* __restrict__ o_part,  // (16,512,32)
    const float* __restrict__ W1,      // (32,609)
    const float* __restrict__ b1,      // (32)
    const float* __restrict__ W2,      // (1,32)
    const float* __restrict__ b2,      // (1)
    float* __restrict__ out)           // (512)
{
    const int t = threadIdx.x;
    const int j = blockIdx.x*4 + (t >> 6);
    const int l = t & 63;
    const int u = l & 31, half = l >> 5;
    const float* frow = &f[j*577];
    const float* wrow = &W1[u*609];
    float p = 0.f;
    for (int a = half; a < 577; a += 2)
        p += frow[a] * wrow[a];
    for (int a = 577 + half; a < 609; a += 2) {
        const int bb = a - 577;
        float ov = 0.f;
        #pragma unroll
        for (int isp = 0; isp < 16; isp++)
            ov += o_part[isp*16384 + j*32 + bb];
        p += ov * wrow[a];
    }
    p += __shfl_xor(p, 32);
    float hid = p + b1[u];
    hid = LRELU(hid);
    float pr = hid * W2[u];
    #pragma unroll
    for (int mk = 16; mk; mk >>= 1) pr += __shfl_xor(pr, mk);
    if (l == 0) out[j] = 1.f / (1.f + __expf(-pr));
}

extern "C" void kernel_launch(void* const* d_in, const int* in_sizes, int n_in,
                              void* d_out, int out_size, void* d_ws, size_t ws_size,
                              hipStream_t stream) {
    const float* readout = (const float*)d_in[0];
    const float* energy  = (const float*)d_in[1];
    const float* w1      = (const float*)d_in[2];
    const float* w2      = (const float*)d_in[3];
    const float* T       = (const float*)d_in[4];
    const float* W1      = (const float*)d_in[5];
    const float* b1      = (const float*)d_in[6];
    const float* W2      = (const float*)d_in[7];
    const float* b2      = (const float*)d_in[8];
    float* out = (float*)d_out;

    char* ws = (char*)d_ws;
    float* f_ws = (float*)(ws);                              // 512*577 f32
    float* M_ws = (float*)(ws + 512*577*4);                  // 512*512 f32
    float* o_ws = (float*)(ws + 512*577*4 + 512*512*4);      // 16*512*32 f32

    convf_kernel   <<<512, 256, 0, stream>>>(readout, energy, w1, w2, f_ws);
    mgemm_kernel   <<<512, 256, 0, stream>>>(f_ws, T, M_ws);
    pairwise_kernel<<<512, 256, 0, stream>>>(M_ws, o_ws);
    mlp_kernel     <<<128, 256, 0, stream>>>(f_ws, o_ws, W1, b1, W2, b2, out);
}

// Round 2
// 87.232 us; speedup vs baseline: 1.2940x; 1.2940x over previous
//
#include <hip/hip_runtime.h>

#define LRELU(v) ((v) >= 0.f ? (v) : 0.2f*(v))

// ---------------- Kernel A: conv stack + f = [hidden(576), |sum(ro)-E|] ----
// Block 0 additionally transposes W1 (32x609) -> W1T (609x32) into ws.
__global__ __launch_bounds__(256) void convf_kernel(
    const float* __restrict__ readout,   // (512,1,9,9)
    const float* __restrict__ energy,    // (512)
    const float* __restrict__ w1,        // (32,1,4,4)
    const float* __restrict__ w2,        // (64,32,4,4)
    const float* __restrict__ W1,        // (32,609)
    float* __restrict__ f_ws,            // (512,577)
    float* __restrict__ W1T)             // (609,32)
{
    const int n = blockIdx.x;
    const int t = threadIdx.x;
    __shared__ float ro[81];
    __shared__ float w1s[512];
    __shared__ float h1[1152];   // [ic(32)][pos(36)]

    if (t < 81) ro[t] = readout[n*81 + t];
    w1s[t] = w1[t];
    w1s[t+256] = w1[t+256];
    __syncthreads();

    // reco_energy on wave 0
    if (t < 64) {
        float s = ro[t];
        if (t < 17) s += ro[t + 64];
        #pragma unroll
        for (int m = 32; m; m >>= 1) s += __shfl_down(s, m);
        if (t == 0) f_ws[n*577 + 576] = fabsf(s - energy[n]);
    }

    // conv1: 32 x 6 x 6
    for (int idx = t; idx < 1152; idx += 256) {
        const int oc = idx / 36, pos = idx % 36;
        const int y = pos / 6, x = pos % 6;
        const float* wp = &w1s[oc*16];
        float a = 0.f;
        #pragma unroll
        for (int ky = 0; ky < 4; ky++)
            #pragma unroll
            for (int kx = 0; kx < 4; kx++)
                a += wp[ky*4 + kx] * ro[(y+ky)*9 + (x+kx)];
        h1[idx] = LRELU(a);
    }
    __syncthreads();

    // conv2: 64 x 3 x 3, 4 output channels per thread (144 active threads)
    if (t < 144) {
        const int ocq = t / 9, pos = t % 9;
        const int y = pos / 3, x = pos % 3;
        const int ocb = ocq * 4;
        float a0 = 0.f, a1 = 0.f, a2 = 0.f, a3 = 0.f;
        for (int ic = 0; ic < 32; ic++) {
            #pragma unroll
            for (int ky = 0; ky < 4; ky++) {
                const int hb = ic*36 + (y+ky)*6 + x;
                const float h0 = h1[hb], hA = h1[hb+1], hB = h1[hb+2], hC = h1[hb+3];
                const float4* w4 = (const float4*)&w2[ocb*512 + ic*16 + ky*4];
                float4 wa = w4[0];
                float4 wb = w4[128];
                float4 wc = w4[256];
                float4 wd = w4[384];
                a0 += wa.x*h0 + wa.y*hA + wa.z*hB + wa.w*hC;
                a1 += wb.x*h0 + wb.y*hA + wb.z*hB + wb.w*hC;
                a2 += wc.x*h0 + wc.y*hA + wc.z*hB + wc.w*hC;
                a3 += wd.x*h0 + wd.y*hA + wd.z*hB + wd.w*hC;
            }
        }
        float* fo = &f_ws[n*577];
        fo[(ocb+0)*9 + pos] = LRELU(a0);
        fo[(ocb+1)*9 + pos] = LRELU(a1);
        fo[(ocb+2)*9 + pos] = LRELU(a2);
        fo[(ocb+3)*9 + pos] = LRELU(a3);
    }

    // W1 transpose (block 0 only; overlapped with other blocks' conv work)
    if (n == 0) {
        for (int idx = t; idx < 609*32; idx += 256) {
            const int u = idx & 31, a = idx >> 5;
            W1T[idx] = W1[u*609 + a];
        }
    }
}

// ---------------- Kernel B: M = F(512x577) @ T(577x512) -------------------
__global__ __launch_bounds__(256) void mgemm_kernel(
    const float* __restrict__ F,
    const float* __restrict__ T,
    float* __restrict__ M)
{
    const int rb = blockIdx.x >> 3;    // 64 row tiles of 8
    const int cb = blockIdx.x & 7;     // 8 col tiles of 64
    const int t = threadIdx.x;
    __shared__ float Fs[8*577];
    const int r0 = rb*8, c0 = cb*64;
    for (int r = 0; r < 8; r++)
        for (int a = t; a < 577; a += 256)
            Fs[r*577 + a] = F[(r0+r)*577 + a];
    __syncthreads();

    const int col = c0 + (t & 63);
    const int rg  = (t >> 6) * 2;      // wave-uniform
    const float* f0 = &Fs[rg*577];
    const float* f1 = &Fs[(rg+1)*577];
    float a0 = 0.f, a1 = 0.f;
    int a = 0;
    for (; a + 4 <= 577; a += 4) {
        float t0 = T[(a+0)*512 + col];
        float t1 = T[(a+1)*512 + col];
        float t2 = T[(a+2)*512 + col];
        float t3 = T[(a+3)*512 + col];
        a0 += f0[a]*t0 + f0[a+1]*t1 + f0[a+2]*t2 + f0[a+3]*t3;
        a1 += f1[a]*t0 + f1[a+1]*t1 + f1[a+2]*t2 + f1[a+3]*t3;
    }
    { // tail (a == 576)
        float tv = T[576*512 + col];
        a0 += f0[576]*tv;
        a1 += f1[576]*tv;
    }
    M[(r0+rg+0)*512 + col] = a0;
    M[(r0+rg+1)*512 + col] = a1;
}

// ---------------- Kernel C: o_part[isp][j][b] = sum_i exp(-L1) ------------
// grid 512: jt = bid>>4 (16 j's each), isp = bid&15 (32 i's each)
__global__ __launch_bounds__(256) void pairwise_kernel(
    const float* __restrict__ M,       // (512,512)
    float* __restrict__ o_part)        // (16,512,32)
{
    const int jt  = blockIdx.x >> 4;
    const int isp = blockIdx.x & 15;
    const int t = threadIdx.x;
    const int b = t & 31, jl = t >> 5;
    const int j0 = jt * 16;
    __shared__ float mi[16*572];       // padded: float off = x + ((x>>5)<<2)

    float m0[16], m1[16];
    {
        const float4* p0 = (const float4*)&M[(j0+jl  )*512 + b*16];
        const float4* p1 = (const float4*)&M[(j0+jl+8)*512 + b*16];
        #pragma unroll
        for (int q = 0; q < 4; q++) {
            float4 v = p0[q];
            m0[4*q+0]=v.x; m0[4*q+1]=v.y; m0[4*q+2]=v.z; m0[4*q+3]=v.w;
            float4 w = p1[q];
            m1[4*q+0]=w.x; m1[4*q+1]=w.y; m1[4*q+2]=w.z; m1[4*q+3]=w.w;
        }
    }

    float acc0 = 0.f, acc1 = 0.f;
    const int lbase = b*16 + ((b>>1)<<2);

    for (int chunk = 0; chunk < 2; chunk++) {
        const int i0 = isp*32 + chunk*16;
        #pragma unroll
        for (int k = 0; k < 8; k++) {
            const int q = k*256 + t;       // 0..2047
            const int r = q >> 7;
            const int x = (q & 127) * 4;
            float4 v = *(const float4*)&M[(i0+r)*512 + x];
            *(float4*)&mi[r*572 + x + ((x>>5)<<2)] = v;
        }
        __syncthreads();
        #pragma unroll 4
        for (int r = 0; r < 16; r++) {
            const float4* q4 = (const float4*)&mi[r*572 + lbase];
            float s0 = 0.f, s1 = 0.f;
            #pragma unroll
            for (int q = 0; q < 4; q++) {
                float4 v = q4[q];
                s0 += fabsf(v.x - m0[4*q+0]) + fabsf(v.y - m0[4*q+1])
                    + fabsf(v.z - m0[4*q+2]) + fabsf(v.w - m0[4*q+3]);
                s1 += fabsf(v.x - m1[4*q+0]) + fabsf(v.y - m1[4*q+1])
                    + fabsf(v.z - m1[4*q+2]) + fabsf(v.w - m1[4*q+3]);
            }
            acc0 += __expf(-s0);
            acc1 += __expf(-s1);
        }
        __syncthreads();
    }
    o_part[isp*16384 + (j0+jl  )*32 + b] = acc0;
    o_part[isp*16384 + (j0+jl+8)*32 + b] = acc1;
}

// ---------------- Kernel D: MLP head, one block per sample -----------------
__global__ __launch_bounds__(256) void mlp_kernel(
    const float* __restrict__ f,       // (512,577)
    const float* __restrict__ o_part,  // (16,512,32)
    const float* __restrict__ W1T,     // (609,32)
    const float* __restrict__ b1,      // (32)
    const float* __restrict__ W2,      // (1,32)
    const float* __restrict__ b2,      // (1)
    float* __restrict__ out)           // (512)
{
    const int j = blockIdx.x;
    const int t = threadIdx.x;
    __shared__ float xs[609];
    __shared__ float red[256];

    for (int a = t; a < 577; a += 256) xs[a] = f[j*577 + a];
    if (t < 32) {
        float ov = 0.f;
        #pragma unroll
        for (int isp = 0; isp < 16; isp++)
            ov += o_part[isp*16384 + j*32 + t];
        xs[577 + t] = ov;
    }
    __syncthreads();

    const int u = t & 31, seg = t >> 5;
    float p = 0.f;
    #pragma unroll 4
    for (int a = seg; a < 609; a += 8)
        p += xs[a] * W1T[a*32 + u];   // xs: LDS broadcast; W1T: coalesced 128B
    red[t] = p;
    __syncthreads();

    if (t < 32) {
        float hid = red[t];
        #pragma unroll
        for (int s = 1; s < 8; s++) hid += red[t + s*32];
        hid += b1[t];
        hid = LRELU(hid);
        float pr = hid * W2[t];
        #pragma unroll
        for (int mk = 16; mk; mk >>= 1) pr += __shfl_xor(pr, mk);
        if (t == 0) out[j] = 1.f / (1.f + __expf(-(pr + b2[0])));
    }
}

extern "C" void kernel_launch(void* const* d_in, const int* in_sizes, int n_in,
                              void* d_out, int out_size, void* d_ws, size_t ws_size,
                              hipStream_t stream) {
    const float* readout = (const float*)d_in[0];
    const float* energy  = (const float*)d_in[1];
    const float* w1      = (const float*)d_in[2];
    const float* w2      = (const float*)d_in[3];
    const float* T       = (const float*)d_in[4];
    const float* W1      = (const float*)d_in[5];
    const float* b1      = (const float*)d_in[6];
    const float* W2      = (const float*)d_in[7];
    const float* b2      = (const float*)d_in[8];
    float* out = (float*)d_out;

    char* ws = (char*)d_ws;
    float* f_ws   = (float*)(ws);                                       // 512*577 f32
    float* M_ws   = (float*)(ws + 512*577*4);                           // 512*512 f32
    float* o_ws   = (float*)(ws + 512*577*4 + 512*512*4);               // 16*512*32 f32
    float* W1T_ws = (float*)(ws + 512*577*4 + 512*512*4 + 16*512*32*4); // 609*32 f32

    convf_kernel   <<<512, 256, 0, stream>>>(readout, energy, w1, w2, W1, f_ws, W1T_ws);
    mgemm_kernel   <<<512, 256, 0, stream>>>(f_ws, T, M_ws);
    pairwise_kernel<<<512, 256, 0, stream>>>(M_ws, o_ws);
    mlp_kernel     <<<512, 256, 0, stream>>>(f_ws, o_ws, W1T_ws, b1, W2, b2, out);
}

// Round 3
// 83.878 us; speedup vs baseline: 1.3458x; 1.0400x over previous
//
#include <hip/hip_runtime.h>

#define LRELU(v) ((v) >= 0.f ? (v) : 0.2f*(v))

// ---------------- Kernel A: conv stack + f = [hidden(576), |sum(ro)-E|] ----
// One block = 2 samples. Thread = (ich = t>>7, s = (t>>6)&1, oc = t&63).
// w2 staged via LDS in 4 ic-chunks of 8, xor-swizzled, reg-prefetched.
// Block 0 additionally transposes W1 (32x609) -> W1T (609x32) into ws.
__global__ __launch_bounds__(256) void convf_kernel(
    const float* __restrict__ readout,   // (512,1,9,9)
    const float* __restrict__ energy,    // (512)
    const float* __restrict__ w1,        // (32,1,4,4)
    const float* __restrict__ w2,        // (64,32,4,4)
    const float* __restrict__ W1,        // (32,609)
    float* __restrict__ f_ws,            // (512,577)
    float* __restrict__ W1T)             // (609,32)
{
    const int n = blockIdx.x;            // samples 2n, 2n+1
    const int t = threadIdx.x;
    __shared__ float ro[162];            // [s][81]
    __shared__ float w1s[512];
    __shared__ float h1[2304];           // [s][ic(32)][pos(36)]
    __shared__ float w2s[8192];          // [oc(64)][128] xor-swizzled (one ic-chunk)
    __shared__ float red[1152];          // [128][9]

    if (t < 162) ro[t] = readout[n*162 + t];
    w1s[t]      = w1[t];
    w1s[t+256]  = w1[t+256];
    __syncthreads();

    // reco_energy: wave0 -> s=0, wave1 -> s=1
    if (t < 128) {
        const int es = t >> 6, l = t & 63;
        float v = ro[es*81 + l];
        if (l < 17) v += ro[es*81 + l + 64];
        #pragma unroll
        for (int m = 32; m; m >>= 1) v += __shfl_down(v, m);
        if (l == 0) f_ws[(2*n+es)*577 + 576] = fabsf(v - energy[2*n+es]);
    }

    // conv1: 2 x 32 x 36 outputs
    for (int idx = t; idx < 2304; idx += 256) {
        const int cs = idx / 1152, rem = idx % 1152;
        const int oc1 = rem / 36, pos = rem % 36;
        const int y = pos / 6, x = pos % 6;
        const float* wp = &w1s[oc1*16];
        const float* rp = &ro[cs*81];
        float a = 0.f;
        #pragma unroll
        for (int ky = 0; ky < 4; ky++)
            #pragma unroll
            for (int kx = 0; kx < 4; kx++)
                a += wp[ky*4 + kx] * rp[(y+ky)*9 + (x+kx)];
        h1[idx] = LRELU(a);
    }

    // prefetch w2 chunk 0 into regs (coalesced float4)
    float4 r[8];
    #pragma unroll
    for (int k = 0; k < 8; k++) {
        const int fidx = t + k*256;            // float4 index within chunk
        const int woc = fidx >> 5, q4 = fidx & 31;
        r[k] = ((const float4*)w2)[woc*128 + q4];
    }
    __syncthreads();                            // h1 ready

    const int ich = t >> 7, s = (t >> 6) & 1, oc = t & 63;
    float acc[9] = {0.f,0.f,0.f,0.f,0.f,0.f,0.f,0.f,0.f};

    for (int chunk = 0; chunk < 4; chunk++) {
        // write prefetched chunk to LDS (xor-swizzled, conflict-free b128)
        #pragma unroll
        for (int k = 0; k < 8; k++) {
            const int fidx = t + k*256;
            const int woc = fidx >> 5, q4 = fidx & 31;
            *((float4*)&w2s[woc*128 + ((q4*4) ^ ((woc & 7) << 2))]) = r[k];
        }
        __syncthreads();
        if (chunk < 3) {                        // prefetch next chunk (hides L2 latency)
            #pragma unroll
            for (int k = 0; k < 8; k++) {
                const int fidx = t + k*256;
                const int woc = fidx >> 5, q4 = fidx & 31;
                r[k] = ((const float4*)w2)[woc*128 + (chunk+1)*32 + q4];
            }
        }
        #pragma unroll
        for (int l = 0; l < 4; l++) {
            const int ic  = chunk*8 + ich*4 + l;   // global input channel
            const int icw = ich*4 + l;             // within chunk
            // h1 row (36 floats) -> regs, broadcast b128 reads
            float hv[36];
            const float4* hp = (const float4*)&h1[s*1152 + ic*36];
            #pragma unroll
            for (int q = 0; q < 9; q++) {
                float4 v = hp[q];
                hv[4*q+0]=v.x; hv[4*q+1]=v.y; hv[4*q+2]=v.z; hv[4*q+3]=v.w;
            }
            #pragma unroll
            for (int ky = 0; ky < 4; ky++) {
                const int col = icw*16 + ky*4;
                float4 w = *((const float4*)&w2s[oc*128 + (col ^ ((oc & 7) << 2))]);
                #pragma unroll
                for (int py = 0; py < 3; py++)
                    #pragma unroll
                    for (int px = 0; px < 3; px++) {
                        const float* hb = &hv[(py+ky)*6 + px];
                        acc[py*3+px] += w.x*hb[0] + w.y*hb[1] + w.z*hb[2] + w.w*hb[3];
                    }
            }
        }
        __syncthreads();
    }

    // reduce the two ic-halves: ich=1 threads dump, ich=0 threads combine+store
    if (t >= 128) {
        #pragma unroll
        for (int p = 0; p < 9; p++) red[(t-128)*9 + p] = acc[p];
    }
    __syncthreads();
    if (t < 128) {
        float* fo = &f_ws[(2*n+s)*577 + oc*9];
        #pragma unroll
        for (int p = 0; p < 9; p++) {
            float v = acc[p] + red[t*9 + p];
            fo[p] = LRELU(v);
        }
    }

    // W1 transpose (block 0 only)
    if (n == 0) {
        for (int idx = t; idx < 609*32; idx += 256) {
            const int u = idx & 31, a = idx >> 5;
            W1T[idx] = W1[u*609 + a];
        }
    }
}

// ---------------- Kernel B: M = F(512x577) @ T(577x512) -------------------
__global__ __launch_bounds__(256) void mgemm_kernel(
    const float* __restrict__ F,
    const float* __restrict__ T,
    float* __restrict__ M)
{
    const int rb = blockIdx.x >> 3;    // 64 row tiles of 8
    const int cb = blockIdx.x & 7;     // 8 col tiles of 64
    const int t = threadIdx.x;
    __shared__ float Fs[8*577];
    const int r0 = rb*8, c0 = cb*64;
    for (int r = 0; r < 8; r++)
        for (int a = t; a < 577; a += 256)
            Fs[r*577 + a] = F[(r0+r)*577 + a];
    __syncthreads();

    const int col = c0 + (t & 63);
    const int rg  = (t >> 6) * 2;      // wave-uniform
    const float* f0 = &Fs[rg*577];
    const float* f1 = &Fs[(rg+1)*577];
    float a0 = 0.f, a1 = 0.f;
    int a = 0;
    for (; a + 4 <= 577; a += 4) {
        float t0 = T[(a+0)*512 + col];
        float t1 = T[(a+1)*512 + col];
        float t2 = T[(a+2)*512 + col];
        float t3 = T[(a+3)*512 + col];
        a0 += f0[a]*t0 + f0[a+1]*t1 + f0[a+2]*t2 + f0[a+3]*t3;
        a1 += f1[a]*t0 + f1[a+1]*t1 + f1[a+2]*t2 + f1[a+3]*t3;
    }
    { // tail (a == 576)
        float tv = T[576*512 + col];
        a0 += f0[576]*tv;
        a1 += f1[576]*tv;
    }
    M[(r0+rg+0)*512 + col] = a0;
    M[(r0+rg+1)*512 + col] = a1;
}

// ---------------- Kernel C: o_part[isp][j][b] = sum_i exp(-L1) ------------
// grid 512: jt = bid>>4 (16 j's each), isp = bid&15 (32 i's each)
__global__ __launch_bounds__(256) void pairwise_kernel(
    const float* __restrict__ M,       // (512,512)
    float* __restrict__ o_part)        // (16,512,32)
{
    const int jt  = blockIdx.x >> 4;
    const int isp = blockIdx.x & 15;
    const int t = threadIdx.x;
    const int b = t & 31, jl = t >> 5;
    const int j0 = jt * 16;
    __shared__ float mi[16*572];       // padded: float off = x + ((x>>5)<<2)

    float m0[16], m1[16];
    {
        const float4* p0 = (const float4*)&M[(j0+jl  )*512 + b*16];
        const float4* p1 = (const float4*)&M[(j0+jl+8)*512 + b*16];
        #pragma unroll
        for (int q = 0; q < 4; q++) {
            float4 v = p0[q];
            m0[4*q+0]=v.x; m0[4*q+1]=v.y; m0[4*q+2]=v.z; m0[4*q+3]=v.w;
            float4 w = p1[q];
            m1[4*q+0]=w.x; m1[4*q+1]=w.y; m1[4*q+2]=w.z; m1[4*q+3]=w.w;
        }
    }

    float acc0 = 0.f, acc1 = 0.f;
    const int lbase = b*16 + ((b>>1)<<2);

    for (int chunk = 0; chunk < 2; chunk++) {
        const int i0 = isp*32 + chunk*16;
        #pragma unroll
        for (int k = 0; k < 8; k++) {
            const int q = k*256 + t;       // 0..2047
            const int r = q >> 7;
            const int x = (q & 127) * 4;
            float4 v = *(const float4*)&M[(i0+r)*512 + x];
            *(float4*)&mi[r*572 + x + ((x>>5)<<2)] = v;
        }
        __syncthreads();
        #pragma unroll 4
        for (int r = 0; r < 16; r++) {
            const float4* q4 = (const float4*)&mi[r*572 + lbase];
            float s0 = 0.f, s1 = 0.f;
            #pragma unroll
            for (int q = 0; q < 4; q++) {
                float4 v = q4[q];
                s0 += fabsf(v.x - m0[4*q+0]) + fabsf(v.y - m0[4*q+1])
                    + fabsf(v.z - m0[4*q+2]) + fabsf(v.w - m0[4*q+3]);
                s1 += fabsf(v.x - m1[4*q+0]) + fabsf(v.y - m1[4*q+1])
                    + fabsf(v.z - m1[4*q+2]) + fabsf(v.w - m1[4*q+3]);
            }
            acc0 += __expf(-s0);
            acc1 += __expf(-s1);
        }
        __syncthreads();
    }
    o_part[isp*16384 + (j0+jl  )*32 + b] = acc0;
    o_part[isp*16384 + (j0+jl+8)*32 + b] = acc1;
}

// ---------------- Kernel D: MLP head, one block per sample -----------------
__global__ __launch_bounds__(256) void mlp_kernel(
    const float* __restrict__ f,       // (512,577)
    const float* __restrict__ o_part,  // (16,512,32)
    const float* __restrict__ W1T,     // (609,32)
    const float* __restrict__ b1,      // (32)
    const float* __restrict__ W2,      // (1,32)
    const float* __restrict__ b2,      // (1)
    float* __restrict__ out)           // (512)
{
    const int j = blockIdx.x;
    const int t = threadIdx.x;
    __shared__ float xs[609];
    __shared__ float red[256];

    for (int a = t; a < 577; a += 256) xs[a] = f[j*577 + a];
    if (t < 32) {
        float ov = 0.f;
        #pragma unroll
        for (int isp = 0; isp < 16; isp++)
            ov += o_part[isp*16384 + j*32 + t];
        xs[577 + t] = ov;
    }
    __syncthreads();

    const int u = t & 31, seg = t >> 5;
    float p = 0.f;
    #pragma unroll 4
    for (int a = seg; a < 609; a += 8)
        p += xs[a] * W1T[a*32 + u];   // xs: LDS broadcast; W1T: coalesced 128B
    red[t] = p;
    __syncthreads();

    if (t < 32) {
        float hid = red[t];
        #pragma unroll
        for (int s = 1; s < 8; s++) hid += red[t + s*32];
        hid += b1[t];
        hid = LRELU(hid);
        float pr = hid * W2[t];
        #pragma unroll
        for (int mk = 16; mk; mk >>= 1) pr += __shfl_xor(pr, mk);
        if (t == 0) out[j] = 1.f / (1.f + __expf(-(pr + b2[0])));
    }
}

extern "C" void kernel_launch(void* const* d_in, const int* in_sizes, int n_in,
                              void* d_out, int out_size, void* d_ws, size_t ws_size,
                              hipStream_t stream) {
    const float* readout = (const float*)d_in[0];
    const float* energy  = (const float*)d_in[1];
    const float* w1      = (const float*)d_in[2];
    const float* w2      = (const float*)d_in[3];
    const float* T       = (const float*)d_in[4];
    const float* W1      = (const float*)d_in[5];
    const float* b1      = (const float*)d_in[6];
    const float* W2      = (const float*)d_in[7];
    const float* b2      = (const float*)d_in[8];
    float* out = (float*)d_out;

    char* ws = (char*)d_ws;
    float* f_ws   = (float*)(ws);                                       // 512*577 f32
    float* M_ws   = (float*)(ws + 512*577*4);                           // 512*512 f32
    float* o_ws   = (float*)(ws + 512*577*4 + 512*512*4);               // 16*512*32 f32
    float* W1T_ws = (float*)(ws + 512*577*4 + 512*512*4 + 16*512*32*4); // 609*32 f32

    convf_kernel   <<<256, 256, 0, stream>>>(readout, energy, w1, w2, W1, f_ws, W1T_ws);
    mgemm_kernel   <<<512, 256, 0, stream>>>(f_ws, T, M_ws);
    pairwise_kernel<<<512, 256, 0, stream>>>(M_ws, o_ws);
    mlp_kernel     <<<512, 256, 0, stream>>>(f_ws, o_ws, W1T_ws, b1, W2, b2, out);
}

// Round 4
// 80.191 us; speedup vs baseline: 1.4077x; 1.0460x over previous
//
#include <hip/hip_runtime.h>

#define LRELU(v) ((v) >= 0.f ? (v) : 0.2f*(v))

// component access into float4 array with compile-time index e (folds at -O3)
#define HV(e) ((e)%4==0 ? h4[(e)/4].x : (e)%4==1 ? h4[(e)/4].y : (e)%4==2 ? h4[(e)/4].z : h4[(e)/4].w)

// ---------------- Kernel A: conv stack + f = [hidden(576), |sum(ro)-E|] ----
// One block = 2 samples. Thread = (ich = t>>7, s = (t>>6)&1, oc = t&63).
// w2 staged via LDS in 4 ic-chunks of 8, xor-swizzled, reg-prefetched.
// Block 0 additionally transposes W1 (32x609) -> W1T (609x32) into ws.
__global__ __launch_bounds__(256) void convf_kernel(
    const float* __restrict__ readout,   // (512,1,9,9)
    const float* __restrict__ energy,    // (512)
    const float* __restrict__ w1,        // (32,1,4,4)
    const float* __restrict__ w2,        // (64,32,4,4)
    const float* __restrict__ W1,        // (32,609)
    float* __restrict__ f_ws,            // (512,577)
    float* __restrict__ W1T)             // (609,32)
{
    const int n = blockIdx.x;            // samples 2n, 2n+1
    const int t = threadIdx.x;
    __shared__ float ro[162];            // [s][81]
    __shared__ float w1s[512];
    __shared__ float h1[2304];           // [s][ic(32)][pos(36)]
    __shared__ float w2s[8192];          // [oc(64)][128] xor-swizzled (one ic-chunk)
    __shared__ float red[1152];          // [128][9]

    if (t < 162) ro[t] = readout[n*162 + t];
    w1s[t]      = w1[t];
    w1s[t+256]  = w1[t+256];
    __syncthreads();

    // reco_energy: wave0 -> s=0, wave1 -> s=1
    if (t < 128) {
        const int es = t >> 6, l = t & 63;
        float v = ro[es*81 + l];
        if (l < 17) v += ro[es*81 + l + 64];
        #pragma unroll
        for (int m = 32; m; m >>= 1) v += __shfl_down(v, m);
        if (l == 0) f_ws[(2*n+es)*577 + 576] = fabsf(v - energy[2*n+es]);
    }

    // conv1: 2 x 32 x 36 outputs
    for (int idx = t; idx < 2304; idx += 256) {
        const int cs = idx / 1152, rem = idx % 1152;
        const int oc1 = rem / 36, pos = rem % 36;
        const int y = pos / 6, x = pos % 6;
        const float* wp = &w1s[oc1*16];
        const float* rp = &ro[cs*81];
        float a = 0.f;
        #pragma unroll
        for (int ky = 0; ky < 4; ky++)
            #pragma unroll
            for (int kx = 0; kx < 4; kx++)
                a += wp[ky*4 + kx] * rp[(y+ky)*9 + (x+kx)];
        h1[idx] = LRELU(a);
    }

    // prefetch w2 chunk 0 into regs (coalesced float4)
    float4 r[8];
    #pragma unroll
    for (int k = 0; k < 8; k++) {
        const int fidx = t + k*256;            // float4 index within chunk
        const int woc = fidx >> 5, q4 = fidx & 31;
        r[k] = ((const float4*)w2)[woc*128 + q4];
    }
    __syncthreads();                            // h1 ready

    const int ich = t >> 7, s = (t >> 6) & 1, oc = t & 63;
    float acc[9] = {0.f,0.f,0.f,0.f,0.f,0.f,0.f,0.f,0.f};

    for (int chunk = 0; chunk < 4; chunk++) {
        // write prefetched chunk to LDS (xor-swizzled, conflict-free b128)
        #pragma unroll
        for (int k = 0; k < 8; k++) {
            const int fidx = t + k*256;
            const int woc = fidx >> 5, q4 = fidx & 31;
            *((float4*)&w2s[woc*128 + ((q4*4) ^ ((woc & 7) << 2))]) = r[k];
        }
        __syncthreads();
        if (chunk < 3) {                        // prefetch next chunk (hides L2 latency)
            #pragma unroll
            for (int k = 0; k < 8; k++) {
                const int fidx = t + k*256;
                const int woc = fidx >> 5, q4 = fidx & 31;
                r[k] = ((const float4*)w2)[woc*128 + (chunk+1)*32 + q4];
            }
        }
        #pragma unroll
        for (int l = 0; l < 4; l++) {
            const int ic  = chunk*8 + ich*4 + l;   // global input channel
            const int icw = ich*4 + l;             // within chunk
            // h1 row (36 floats) -> 9 float4 regs, broadcast b128 reads
            float4 h4[9];
            const float4* hp = (const float4*)&h1[s*1152 + ic*36];
            #pragma unroll
            for (int q = 0; q < 9; q++) h4[q] = hp[q];
            #pragma unroll
            for (int ky = 0; ky < 4; ky++) {
                const int col = icw*16 + ky*4;
                float4 w = *((const float4*)&w2s[oc*128 + (col ^ ((oc & 7) << 2))]);
                #pragma unroll
                for (int py = 0; py < 3; py++) {
                    #pragma unroll
                    for (int px = 0; px < 3; px++) {
                        const int e = (py+ky)*6 + px;
                        acc[py*3+px] += w.x*HV(e) + w.y*HV(e+1)
                                      + w.z*HV(e+2) + w.w*HV(e+3);
                    }
                }
            }
        }
        __syncthreads();
    }

    // reduce the two ic-halves: ich=1 threads dump, ich=0 threads combine+store
    if (t >= 128) {
        #pragma unroll
        for (int p = 0; p < 9; p++) red[(t-128)*9 + p] = acc[p];
    }
    __syncthreads();
    if (t < 128) {
        float* fo = &f_ws[(2*n+s)*577 + oc*9];
        #pragma unroll
        for (int p = 0; p < 9; p++) {
            float v = acc[p] + red[t*9 + p];
            fo[p] = LRELU(v);
        }
    }

    // W1 transpose (block 0 only)
    if (n == 0) {
        for (int idx = t; idx < 609*32; idx += 256) {
            const int u = idx & 31, a = idx >> 5;
            W1T[idx] = W1[u*609 + a];
        }
    }
}

// ---------------- Kernel B: M = F(512x577) @ T(577x512) -------------------
__global__ __launch_bounds__(256) void mgemm_kernel(
    const float* __restrict__ F,
    const float* __restrict__ T,
    float* __restrict__ M)
{
    const int rb = blockIdx.x >> 3;    // 64 row tiles of 8
    const int cb = blockIdx.x & 7;     // 8 col tiles of 64
    const int t = threadIdx.x;
    __shared__ float Fs[8*577];
    const int r0 = rb*8, c0 = cb*64;
    for (int r = 0; r < 8; r++)
        for (int a = t; a < 577; a += 256)
            Fs[r*577 + a] = F[(r0+r)*577 + a];
    __syncthreads();

    const int col = c0 + (t & 63);
    const int rg  = (t >> 6) * 2;      // wave-uniform
    const float* f0 = &Fs[rg*577];
    const float* f1 = &Fs[(rg+1)*577];
    float a0 = 0.f, a1 = 0.f;
    int a = 0;
    for (; a + 4 <= 577; a += 4) {
        float t0 = T[(a+0)*512 + col];
        float t1 = T[(a+1)*512 + col];
        float t2 = T[(a+2)*512 + col];
        float t3 = T[(a+3)*512 + col];
        a0 += f0[a]*t0 + f0[a+1]*t1 + f0[a+2]*t2 + f0[a+3]*t3;
        a1 += f1[a]*t0 + f1[a+1]*t1 + f1[a+2]*t2 + f1[a+3]*t3;
    }
    { // tail (a == 576)
        float tv = T[576*512 + col];
        a0 += f0[576]*tv;
        a1 += f1[576]*tv;
    }
    M[(r0+rg+0)*512 + col] = a0;
    M[(r0+rg+1)*512 + col] = a1;
}

// ---------------- Kernel C: o_part[isp][j][b] = sum_i exp(-L1) ------------
// grid 512: jt = bid>>4 (16 j's each), isp = bid&15 (32 i's each)
__global__ __launch_bounds__(256) void pairwise_kernel(
    const float* __restrict__ M,       // (512,512)
    float* __restrict__ o_part)        // (16,512,32)
{
    const int jt  = blockIdx.x >> 4;
    const int isp = blockIdx.x & 15;
    const int t = threadIdx.x;
    const int b = t & 31, jl = t >> 5;
    const int j0 = jt * 16;
    __shared__ float mi[16*572];       // padded: float off = x + ((x>>5)<<2)

    float m0[16], m1[16];
    {
        const float4* p0 = (const float4*)&M[(j0+jl  )*512 + b*16];
        const float4* p1 = (const float4*)&M[(j0+jl+8)*512 + b*16];
        #pragma unroll
        for (int q = 0; q < 4; q++) {
            float4 v = p0[q];
            m0[4*q+0]=v.x; m0[4*q+1]=v.y; m0[4*q+2]=v.z; m0[4*q+3]=v.w;
            float4 w = p1[q];
            m1[4*q+0]=w.x; m1[4*q+1]=w.y; m1[4*q+2]=w.z; m1[4*q+3]=w.w;
        }
    }

    float acc0 = 0.f, acc1 = 0.f;
    const int lbase = b*16 + ((b>>1)<<2);

    for (int chunk = 0; chunk < 2; chunk++) {
        const int i0 = isp*32 + chunk*16;
        #pragma unroll
        for (int k = 0; k < 8; k++) {
            const int q = k*256 + t;       // 0..2047
            const int r = q >> 7;
            const int x = (q & 127) * 4;
            float4 v = *(const float4*)&M[(i0+r)*512 + x];
            *(float4*)&mi[r*572 + x + ((x>>5)<<2)] = v;
        }
        __syncthreads();
        #pragma unroll 4
        for (int r = 0; r < 16; r++) {
            const float4* q4 = (const float4*)&mi[r*572 + lbase];
            float s0 = 0.f, s1 = 0.f;
            #pragma unroll
            for (int q = 0; q < 4; q++) {
                float4 v = q4[q];
                s0 += fabsf(v.x - m0[4*q+0]) + fabsf(v.y - m0[4*q+1])
                    + fabsf(v.z - m0[4*q+2]) + fabsf(v.w - m0[4*q+3]);
                s1 += fabsf(v.x - m1[4*q+0]) + fabsf(v.y - m1[4*q+1])
                    + fabsf(v.z - m1[4*q+2]) + fabsf(v.w - m1[4*q+3]);
            }
            acc0 += __expf(-s0);
            acc1 += __expf(-s1);
        }
        __syncthreads();
    }
    o_part[isp*16384 + (j0+jl  )*32 + b] = acc0;
    o_part[isp*16384 + (j0+jl+8)*32 + b] = acc1;
}

// ---------------- Kernel D: MLP head, one block per sample -----------------
__global__ __launch_bounds__(256) void mlp_kernel(
    const float* __restrict__ f,       // (512,577)
    const float* __restrict__ o_part,  // (16,512,32)
    const float* __restrict__ W1T,     // (609,32)
    const float* __restrict__ b1,      // (32)
    const float* __restrict__ W2,      // (1,32)
    const float* __restrict__ b2,      // (1)
    float* __restrict__ out)           // (512)
{
    const int j = blockIdx.x;
    const int t = threadIdx.x;
    __shared__ float xs[609];
    __shared__ float red[256];

    for (int a = t; a < 577; a += 256) xs[a] = f[j*577 + a];
    if (t < 32) {
        float ov = 0.f;
        #pragma unroll
        for (int isp = 0; isp < 16; isp++)
            ov += o_part[isp*16384 + j*32 + t];
        xs[577 + t] = ov;
    }
    __syncthreads();

    const int u = t & 31, seg = t >> 5;
    float p = 0.f;
    #pragma unroll 4
    for (int a = seg; a < 609; a += 8)
        p += xs[a] * W1T[a*32 + u];   // xs: LDS broadcast; W1T: coalesced 128B
    red[t] = p;
    __syncthreads();

    if (t < 32) {
        float hid = red[t];
        #pragma unroll
        for (int s = 1; s < 8; s++) hid += red[t + s*32];
        hid += b1[t];
        hid = LRELU(hid);
        float pr = hid * W2[t];
        #pragma unroll
        for (int mk = 16; mk; mk >>= 1) pr += __shfl_xor(pr, mk);
        if (t == 0) out[j] = 1.f / (1.f + __expf(-(pr + b2[0])));
    }
}

extern "C" void kernel_launch(void* const* d_in, const int* in_sizes, int n_in,
                              void* d_out, int out_size, void* d_ws, size_t ws_size,
                              hipStream_t stream) {
    const float* readout = (const float*)d_in[0];
    const float* energy  = (const float*)d_in[1];
    const float* w1      = (const float*)d_in[2];
    const float* w2      = (const float*)d_in[3];
    const float* T       = (const float*)d_in[4];
    const float* W1      = (const float*)d_in[5];
    const float* b1      = (const float*)d_in[6];
    const float* W2      = (const float*)d_in[7];
    const float* b2      = (const float*)d_in[8];
    float* out = (float*)d_out;

    char* ws = (char*)d_ws;
    float* f_ws   = (float*)(ws);                                       // 512*577 f32
    float* M_ws   = (float*)(ws + 512*577*4);                           // 512*512 f32
    float* o_ws   = (float*)(ws + 512*577*4 + 512*512*4);               // 16*512*32 f32
    float* W1T_ws = (float*)(ws + 512*577*4 + 512*512*4 + 16*512*32*4); // 609*32 f32

    convf_kernel   <<<256, 256, 0, stream>>>(readout, energy, w1, w2, W1, f_ws, W1T_ws);
    mgemm_kernel   <<<512, 256, 0, stream>>>(f_ws, T, M_ws);
    pairwise_kernel<<<512, 256, 0, stream>>>(M_ws, o_ws);
    mlp_kernel     <<<512, 256, 0, stream>>>(f_ws, o_ws, W1T_ws, b1, W2, b2, out);
}

// Round 5
// 66.645 us; speedup vs baseline: 1.6938x; 1.2033x over previous
//
#include <hip/hip_runtime.h>

#define LRELU(v) ((v) >= 0.f ? (v) : 0.2f*(v))

// ---- named-register h-row access: E<i> = element i of the 36-float h row --
#define E0 q0.x
#define E1 q0.y
#define E2 q0.z
#define E3 q0.w
#define E4 q1.x
#define E5 q1.y
#define E6 q1.z
#define E7 q1.w
#define E8 q2.x
#define E9 q2.y
#define E10 q2.z
#define E11 q2.w
#define E12 q3.x
#define E13 q3.y
#define E14 q3.z
#define E15 q3.w
#define E16 q4.x
#define E17 q4.y
#define E18 q4.z
#define E19 q4.w
#define E20 q5.x
#define E21 q5.y
#define E22 q5.z
#define E23 q5.w
#define E24 q6.x
#define E25 q6.y
#define E26 q6.z
#define E27 q6.w
#define E28 q7.x
#define E29 q7.y
#define E30 q7.z
#define E31 q7.w
#define E32 q8.x
#define E33 q8.y
#define E34 q8.z
#define E35 q8.w

// acc P += dot(w, h[eA..eD])  (all indices are preprocessor literals)
#define AT(P, A, B, C, D) a##P += w.x*E##A + w.y*E##B + w.z*E##C + w.w*E##D;

// w2 chunk staging, fully named regs (no arrays -> no scratch)
#define LD1(RK, K, BASE) { const int fidx_ = t + (K)*256; \
    const int woc_ = fidx_ >> 5, q4_ = fidx_ & 31; \
    RK = ((const float4*)w2)[woc_*128 + (BASE) + q4_]; }
#define LDALL(BASE) LD1(r0,0,BASE) LD1(r1,1,BASE) LD1(r2,2,BASE) LD1(r3,3,BASE) \
                    LD1(r4,4,BASE) LD1(r5,5,BASE) LD1(r6,6,BASE) LD1(r7,7,BASE)
#define ST1(RK, K) { const int fidx_ = t + (K)*256; \
    const int woc_ = fidx_ >> 5, q4_ = fidx_ & 31; \
    *((float4*)&w2s[woc_*128 + ((q4_*4) ^ ((woc_ & 7) << 2))]) = RK; }
#define STALL ST1(r0,0) ST1(r1,1) ST1(r2,2) ST1(r3,3) ST1(r4,4) ST1(r5,5) ST1(r6,6) ST1(r7,7)

// ---------------- Kernel A: conv stack + f = [hidden(576), |sum(ro)-E|] ----
// One block = 2 samples. Thread = (ich = t>>7, s = (t>>6)&1, oc = t&63).
// w2 staged via LDS in 4 ic-chunks of 8, xor-swizzled, reg-prefetched.
// ZERO local arrays (rule #20): named regs only.
__global__ __launch_bounds__(256) void convf_kernel(
    const float* __restrict__ readout,   // (512,1,9,9)
    const float* __restrict__ energy,    // (512)
    const float* __restrict__ w1,        // (32,1,4,4)
    const float* __restrict__ w2,        // (64,32,4,4)
    const float* __restrict__ W1,        // (32,609)
    float* __restrict__ f_ws,            // (512,577)
    float* __restrict__ W1T)             // (609,32)
{
    const int n = blockIdx.x;            // samples 2n, 2n+1
    const int t = threadIdx.x;
    __shared__ float ro[162];            // [s][81]
    __shared__ float w1s[512];
    __shared__ float h1[2304];           // [s][ic(32)][pos(36)]
    __shared__ float w2s[8192];          // [oc(64)][128] xor-swizzled (one ic-chunk)
    __shared__ float red[1152];          // [128][9]

    if (t < 162) ro[t] = readout[n*162 + t];
    w1s[t]      = w1[t];
    w1s[t+256]  = w1[t+256];
    __syncthreads();

    // reco_energy: wave0 -> s=0, wave1 -> s=1
    if (t < 128) {
        const int es = t >> 6, l = t & 63;
        float v = ro[es*81 + l];
        if (l < 17) v += ro[es*81 + l + 64];
        #pragma unroll
        for (int m = 32; m; m >>= 1) v += __shfl_down(v, m);
        if (l == 0) f_ws[(2*n+es)*577 + 576] = fabsf(v - energy[2*n+es]);
    }

    // conv1: 2 x 32 x 36 outputs (scalars only)
    for (int idx = t; idx < 2304; idx += 256) {
        const int cs = idx / 1152, rem = idx % 1152;
        const int oc1 = rem / 36, pos = rem % 36;
        const int y = pos / 6, x = pos % 6;
        const float* wp = &w1s[oc1*16];
        const float* rp = &ro[cs*81];
        float a = 0.f;
        #pragma unroll
        for (int ky = 0; ky < 4; ky++)
            #pragma unroll
            for (int kx = 0; kx < 4; kx++)
                a += wp[ky*4 + kx] * rp[(y+ky)*9 + (x+kx)];
        h1[idx] = LRELU(a);
    }

    // prefetch w2 chunk 0 into named regs (coalesced float4)
    float4 r0, r1, r2, r3, r4, r5, r6, r7;
    LDALL(0)
    __syncthreads();                            // h1 ready

    const int ich = t >> 7, s = (t >> 6) & 1, oc = t & 63;
    float a0=0.f,a1=0.f,a2=0.f,a3=0.f,a4=0.f,a5=0.f,a6=0.f,a7=0.f,a8=0.f;
    const int hbase = s*1152;
    const int wbase = oc*128;
    const int wswz  = (oc & 7) << 2;

    for (int chunk = 0; chunk < 4; chunk++) {
        STALL                                   // publish chunk to LDS (swizzled)
        __syncthreads();
        if (chunk < 3) { LDALL((chunk+1)*32) }  // prefetch next (hides L2 latency)

        #pragma unroll
        for (int l = 0; l < 4; l++) {
            const int icw = ich*4 + l;          // within chunk
            const int ic  = chunk*8 + icw;      // global input channel
            // h1 row (36 floats) -> 9 named float4, uniform broadcast b128
            const float4* hp = (const float4*)&h1[hbase + ic*36];
            float4 q0=hp[0], q1=hp[1], q2=hp[2], q3=hp[3], q4=hp[4],
                   q5=hp[5], q6=hp[6], q7=hp[7], q8=hp[8];
            { // ky = 0
                float4 w = *((const float4*)&w2s[wbase + ((icw*16 + 0) ^ wswz)]);
                AT(0, 0,1,2,3)    AT(1, 1,2,3,4)    AT(2, 2,3,4,5)
                AT(3, 6,7,8,9)    AT(4, 7,8,9,10)   AT(5, 8,9,10,11)
                AT(6, 12,13,14,15) AT(7, 13,14,15,16) AT(8, 14,15,16,17)
            }
            { // ky = 1
                float4 w = *((const float4*)&w2s[wbase + ((icw*16 + 4) ^ wswz)]);
                AT(0, 6,7,8,9)    AT(1, 7,8,9,10)   AT(2, 8,9,10,11)
                AT(3, 12,13,14,15) AT(4, 13,14,15,16) AT(5, 14,15,16,17)
                AT(6, 18,19,20,21) AT(7, 19,20,21,22) AT(8, 20,21,22,23)
            }
            { // ky = 2
                float4 w = *((const float4*)&w2s[wbase + ((icw*16 + 8) ^ wswz)]);
                AT(0, 12,13,14,15) AT(1, 13,14,15,16) AT(2, 14,15,16,17)
                AT(3, 18,19,20,21) AT(4, 19,20,21,22) AT(5, 20,21,22,23)
                AT(6, 24,25,26,27) AT(7, 25,26,27,28) AT(8, 26,27,28,29)
            }
            { // ky = 3
                float4 w = *((const float4*)&w2s[wbase + ((icw*16 + 12) ^ wswz)]);
                AT(0, 18,19,20,21) AT(1, 19,20,21,22) AT(2, 20,21,22,23)
                AT(3, 24,25,26,27) AT(4, 25,26,27,28) AT(5, 26,27,28,29)
                AT(6, 30,31,32,33) AT(7, 31,32,33,34) AT(8, 32,33,34,35)
            }
        }
        __syncthreads();
    }

    // reduce the two ic-halves: ich=1 threads dump, ich=0 threads combine+store
    if (t >= 128) {
        float* rp = &red[(t-128)*9];
        rp[0]=a0; rp[1]=a1; rp[2]=a2; rp[3]=a3; rp[4]=a4;
        rp[5]=a5; rp[6]=a6; rp[7]=a7; rp[8]=a8;
    }
    __syncthreads();
    if (t < 128) {
        const float* rp = &red[t*9];
        float* fo = &f_ws[(2*n+s)*577 + oc*9];
        float v;
        v = a0 + rp[0]; fo[0] = LRELU(v);
        v = a1 + rp[1]; fo[1] = LRELU(v);
        v = a2 + rp[2]; fo[2] = LRELU(v);
        v = a3 + rp[3]; fo[3] = LRELU(v);
        v = a4 + rp[4]; fo[4] = LRELU(v);
        v = a5 + rp[5]; fo[5] = LRELU(v);
        v = a6 + rp[6]; fo[6] = LRELU(v);
        v = a7 + rp[7]; fo[7] = LRELU(v);
        v = a8 + rp[8]; fo[8] = LRELU(v);
    }

    // W1 transpose (block 0 only)
    if (n == 0) {
        for (int idx = t; idx < 609*32; idx += 256) {
            const int u = idx & 31, a = idx >> 5;
            W1T[idx] = W1[u*609 + a];
        }
    }
}

// ---------------- Kernel B: M = F(512x577) @ T(577x512) -------------------
__global__ __launch_bounds__(256) void mgemm_kernel(
    const float* __restrict__ F,
    const float* __restrict__ T,
    float* __restrict__ M)
{
    const int rb = blockIdx.x >> 3;    // 64 row tiles of 8
    const int cb = blockIdx.x & 7;     // 8 col tiles of 64
    const int t = threadIdx.x;
    __shared__ float Fs[8*577];
    const int r0 = rb*8, c0 = cb*64;
    for (int r = 0; r < 8; r++)
        for (int a = t; a < 577; a += 256)
            Fs[r*577 + a] = F[(r0+r)*577 + a];
    __syncthreads();

    const int col = c0 + (t & 63);
    const int rg  = (t >> 6) * 2;      // wave-uniform
    const float* f0 = &Fs[rg*577];
    const float* f1 = &Fs[(rg+1)*577];
    float a0 = 0.f, a1 = 0.f;
    int a = 0;
    for (; a + 4 <= 577; a += 4) {
        float t0 = T[(a+0)*512 + col];
        float t1 = T[(a+1)*512 + col];
        float t2 = T[(a+2)*512 + col];
        float t3 = T[(a+3)*512 + col];
        a0 += f0[a]*t0 + f0[a+1]*t1 + f0[a+2]*t2 + f0[a+3]*t3;
        a1 += f1[a]*t0 + f1[a+1]*t1 + f1[a+2]*t2 + f1[a+3]*t3;
    }
    { // tail (a == 576)
        float tv = T[576*512 + col];
        a0 += f0[576]*tv;
        a1 += f1[576]*tv;
    }
    M[(r0+rg+0)*512 + col] = a0;
    M[(r0+rg+1)*512 + col] = a1;
}

// ---------------- Kernel C: o_part[isp][j][b] = sum_i exp(-L1) ------------
// grid 512: jt = bid>>4 (16 j's each), isp = bid&15 (32 i's each)
__global__ __launch_bounds__(256) void pairwise_kernel(
    const float* __restrict__ M,       // (512,512)
    float* __restrict__ o_part)        // (16,512,32)
{
    const int jt  = blockIdx.x >> 4;
    const int isp = blockIdx.x & 15;
    const int t = threadIdx.x;
    const int b = t & 31, jl = t >> 5;
    const int j0 = jt * 16;
    __shared__ float mi[16*572];       // padded: float off = x + ((x>>5)<<2)

    float m0[16], m1[16];
    {
        const float4* p0 = (const float4*)&M[(j0+jl  )*512 + b*16];
        const float4* p1 = (const float4*)&M[(j0+jl+8)*512 + b*16];
        #pragma unroll
        for (int q = 0; q < 4; q++) {
            float4 v = p0[q];
            m0[4*q+0]=v.x; m0[4*q+1]=v.y; m0[4*q+2]=v.z; m0[4*q+3]=v.w;
            float4 w = p1[q];
            m1[4*q+0]=w.x; m1[4*q+1]=w.y; m1[4*q+2]=w.z; m1[4*q+3]=w.w;
        }
    }

    float acc0 = 0.f, acc1 = 0.f;
    const int lbase = b*16 + ((b>>1)<<2);

    for (int chunk = 0; chunk < 2; chunk++) {
        const int i0 = isp*32 + chunk*16;
        #pragma unroll
        for (int k = 0; k < 8; k++) {
            const int q = k*256 + t;       // 0..2047
            const int r = q >> 7;
            const int x = (q & 127) * 4;
            float4 v = *(const float4*)&M[(i0+r)*512 + x];
            *(float4*)&mi[r*572 + x + ((x>>5)<<2)] = v;
        }
        __syncthreads();
        #pragma unroll 4
        for (int r = 0; r < 16; r++) {
            const float4* q4 = (const float4*)&mi[r*572 + lbase];
            float s0 = 0.f, s1 = 0.f;
            #pragma unroll
            for (int q = 0; q < 4; q++) {
                float4 v = q4[q];
                s0 += fabsf(v.x - m0[4*q+0]) + fabsf(v.y - m0[4*q+1])
                    + fabsf(v.z - m0[4*q+2]) + fabsf(v.w - m0[4*q+3]);
                s1 += fabsf(v.x - m1[4*q+0]) + fabsf(v.y - m1[4*q+1])
                    + fabsf(v.z - m1[4*q+2]) + fabsf(v.w - m1[4*q+3]);
            }
            acc0 += __expf(-s0);
            acc1 += __expf(-s1);
        }
        __syncthreads();
    }
    o_part[isp*16384 + (j0+jl  )*32 + b] = acc0;
    o_part[isp*16384 + (j0+jl+8)*32 + b] = acc1;
}

// ---------------- Kernel D: MLP head, one block per sample -----------------
__global__ __launch_bounds__(256) void mlp_kernel(
    const float* __restrict__ f,       // (512,577)
    const float* __restrict__ o_part,  // (16,512,32)
    const float* __restrict__ W1T,     // (609,32)
    const float* __restrict__ b1,      // (32)
    const float* __restrict__ W2,      // (1,32)
    const float* __restrict__ b2,      // (1)
    float* __restrict__ out)           // (512)
{
    const int j = blockIdx.x;
    const int t = threadIdx.x;
    __shared__ float xs[609];
    __shared__ float red[256];

    for (int a = t; a < 577; a += 256) xs[a] = f[j*577 + a];
    if (t < 32) {
        float ov = 0.f;
        #pragma unroll
        for (int isp = 0; isp < 16; isp++)
            ov += o_part[isp*16384 + j*32 + t];
        xs[577 + t] = ov;
    }
    __syncthreads();

    const int u = t & 31, seg = t >> 5;
    float p = 0.f;
    #pragma unroll 4
    for (int a = seg; a < 609; a += 8)
        p += xs[a] * W1T[a*32 + u];   // xs: LDS broadcast; W1T: coalesced 128B
    red[t] = p;
    __syncthreads();

    if (t < 32) {
        float hid = red[t];
        #pragma unroll
        for (int s = 1; s < 8; s++) hid += red[t + s*32];
        hid += b1[t];
        hid = LRELU(hid);
        float pr = hid * W2[t];
        #pragma unroll
        for (int mk = 16; mk; mk >>= 1) pr += __shfl_xor(pr, mk);
        if (t == 0) out[j] = 1.f / (1.f + __expf(-(pr + b2[0])));
    }
}

extern "C" void kernel_launch(void* const* d_in, const int* in_sizes, int n_in,
                              void* d_out, int out_size, void* d_ws, size_t ws_size,
                              hipStream_t stream) {
    const float* readout = (const float*)d_in[0];
    const float* energy  = (const float*)d_in[1];
    const float* w1      = (const float*)d_in[2];
    const float* w2      = (const float*)d_in[3];
    const float* T       = (const float*)d_in[4];
    const float* W1      = (const float*)d_in[5];
    const float* b1      = (const float*)d_in[6];
    const float* W2      = (const float*)d_in[7];
    const float* b2      = (const float*)d_in[8];
    float* out = (float*)d_out;

    char* ws = (char*)d_ws;
    float* f_ws   = (float*)(ws);                                       // 512*577 f32
    float* M_ws   = (float*)(ws + 512*577*4);                           // 512*512 f32
    float* o_ws   = (float*)(ws + 512*577*4 + 512*512*4);               // 16*512*32 f32
    float* W1T_ws = (float*)(ws + 512*577*4 + 512*512*4 + 16*512*32*4); // 609*32 f32

    convf_kernel   <<<256, 256, 0, stream>>>(readout, energy, w1, w2, W1, f_ws, W1T_ws);
    mgemm_kernel   <<<512, 256, 0, stream>>>(f_ws, T, M_ws);
    pairwise_kernel<<<512, 256, 0, stream>>>(M_ws, o_ws);
    mlp_kernel     <<<512, 256, 0, stream>>>(f_ws, o_ws, W1T_ws, b1, W2, b2, out);
}

// Round 7
// 57.696 us; speedup vs baseline: 1.9565x; 1.1551x over previous
//
#include <hip/hip_runtime.h>

#define LRELU(v) ((v) >= 0.f ? (v) : 0.2f*(v))

// ---- named-register h-row access: E<i> = element i of the 36-float h row --
#define E0 q0.x
#define E1 q0.y
#define E2 q0.z
#define E3 q0.w
#define E4 q1.x
#define E5 q1.y
#define E6 q1.z
#define E7 q1.w
#define E8 q2.x
#define E9 q2.y
#define E10 q2.z
#define E11 q2.w
#define E12 q3.x
#define E13 q3.y
#define E14 q3.z
#define E15 q3.w
#define E16 q4.x
#define E17 q4.y
#define E18 q4.z
#define E19 q4.w
#define E20 q5.x
#define E21 q5.y
#define E22 q5.z
#define E23 q5.w
#define E24 q6.x
#define E25 q6.y
#define E26 q6.z
#define E27 q6.w
#define E28 q7.x
#define E29 q7.y
#define E30 q7.z
#define E31 q7.w
#define E32 q8.x
#define E33 q8.y
#define E34 q8.z
#define E35 q8.w

// acc P += dot(w, h[eA..eD])  (all indices are preprocessor literals)
#define AT(P, A, B, C, D) a##P += w.x*E##A + w.y*E##B + w.z*E##C + w.w*E##D;

// w2 chunk staging (32-oc slice), fully named regs (no arrays -> no scratch)
#define LD1(RK, K, BASE) { const int fidx_ = t + (K)*256; \
    const int woc_ = fidx_ >> 5, q4_ = fidx_ & 31; \
    RK = ((const float4*)w2)[(oc0 + woc_)*128 + (BASE) + q4_]; }
#define LDALL(BASE) LD1(r0,0,BASE) LD1(r1,1,BASE) LD1(r2,2,BASE) LD1(r3,3,BASE)
#define ST1(RK, K) { const int fidx_ = t + (K)*256; \
    const int woc_ = fidx_ >> 5, q4_ = fidx_ & 31; \
    *((float4*)&w2s[woc_*128 + ((q4_*4) ^ ((woc_ & 7) << 2))]) = RK; }
#define STALL ST1(r0,0) ST1(r1,1) ST1(r2,2) ST1(r3,3)

// ---------------- Kernel A: conv stack + f = [hidden(576), |sum(ro)-E|] ----
// Grid 1024: block = (sample n = bid>>1) x (oc-half och = bid&1).
// Thread = (ich = t>>5 in 0..7, ocl = t&31). Per chunk of 8 ic, each thread
// owns 1 ic. 32KB LDS -> 4 blocks/CU, 4 waves/SIMD.
__global__ __launch_bounds__(256) void convf_kernel(
    const float* __restrict__ readout,   // (512,1,9,9)
    const float* __restrict__ energy,    // (512)
    const float* __restrict__ w1,        // (32,1,4,4)
    const float* __restrict__ w2,        // (64,32,4,4)
    const float* __restrict__ W1,        // (32,609)
    float* __restrict__ f_ws,            // (512,577)
    float* __restrict__ W1T)             // (609,32)
{
    const int bid = blockIdx.x;
    const int n   = bid >> 1;
    const int och = bid & 1;
    const int oc0 = och << 5;            // 0 or 32 (w2 row base)
    const int t = threadIdx.x;
    __shared__ float ro[81];
    __shared__ float w1s[512];
    __shared__ float h1[1152];           // [ic(32)][pos(36)]
    __shared__ float w2s[4096];          // [ocl(32)][128] xor-swizzled chunk
    __shared__ float red[2304];          // [ich(8)][ocl(32)][9]

    if (t < 81) ro[t] = readout[n*81 + t];
    w1s[t]      = w1[t];
    w1s[t+256]  = w1[t+256];
    __syncthreads();

    // reco_energy (only och=0 blocks, wave 0)
    if (och == 0 && t < 64) {
        float v = ro[t];
        if (t < 17) v += ro[t + 64];
        #pragma unroll
        for (int m = 32; m; m >>= 1) v += __shfl_down(v, m);
        if (t == 0) f_ws[n*577 + 576] = fabsf(v - energy[n]);
    }

    // conv1: 32 x 6 x 6 (scalars only)
    for (int idx = t; idx < 1152; idx += 256) {
        const int oc1 = idx / 36, pos = idx % 36;
        const int y = pos / 6, x = pos % 6;
        const float* wp = &w1s[oc1*16];
        float a = 0.f;
        #pragma unroll
        for (int ky = 0; ky < 4; ky++)
            #pragma unroll
            for (int kx = 0; kx < 4; kx++)
                a += wp[ky*4 + kx] * ro[(y+ky)*9 + (x+kx)];
        h1[idx] = LRELU(a);
    }

    // prefetch w2 chunk 0 (coalesced float4, 4/thread)
    float4 r0, r1, r2, r3;
    LDALL(0)
    __syncthreads();                            // h1 ready

    const int ich = t >> 5, ocl = t & 31;
    float a0=0.f,a1=0.f,a2=0.f,a3=0.f,a4=0.f,a5=0.f,a6=0.f,a7=0.f,a8=0.f;
    const int wbase = ocl*128;
    const int wswz  = (ocl & 7) << 2;

    for (int chunk = 0; chunk < 4; chunk++) {
        STALL                                   // publish chunk to LDS (swizzled)
        __syncthreads();
        if (chunk < 3) { LDALL((chunk+1)*32) }  // prefetch next (hides L2 latency)

        {
            const int icw = ich;                // 1 ic per thread per chunk
            const int ic  = chunk*8 + ich;
            const float4* hp = (const float4*)&h1[ic*36];
            float4 q0=hp[0], q1=hp[1], q2=hp[2], q3=hp[3], q4=hp[4],
                   q5=hp[5], q6=hp[6], q7=hp[7], q8=hp[8];
            { // ky = 0
                float4 w = *((const float4*)&w2s[wbase + ((icw*16 + 0) ^ wswz)]);
                AT(0, 0,1,2,3)    AT(1, 1,2,3,4)    AT(2, 2,3,4,5)
                AT(3, 6,7,8,9)    AT(4, 7,8,9,10)   AT(5, 8,9,10,11)
                AT(6, 12,13,14,15) AT(7, 13,14,15,16) AT(8, 14,15,16,17)
            }
            { // ky = 1
                float4 w = *((const float4*)&w2s[wbase + ((icw*16 + 4) ^ wswz)]);
                AT(0, 6,7,8,9)    AT(1, 7,8,9,10)   AT(2, 8,9,10,11)
                AT(3, 12,13,14,15) AT(4, 13,14,15,16) AT(5, 14,15,16,17)
                AT(6, 18,19,20,21) AT(7, 19,20,21,22) AT(8, 20,21,22,23)
            }
            { // ky = 2
                float4 w = *((const float4*)&w2s[wbase + ((icw*16 + 8) ^ wswz)]);
                AT(0, 12,13,14,15) AT(1, 13,14,15,16) AT(2, 14,15,16,17)
                AT(3, 18,19,20,21) AT(4, 19,20,21,22) AT(5, 20,21,22,23)
                AT(6, 24,25,26,27) AT(7, 25,26,27,28) AT(8, 26,27,28,29)
            }
            { // ky = 3
                float4 w = *((const float4*)&w2s[wbase + ((icw*16 + 12) ^ wswz)]);
                AT(0, 18,19,20,21) AT(1, 19,20,21,22) AT(2, 20,21,22,23)
                AT(3, 24,25,26,27) AT(4, 25,26,27,28) AT(5, 26,27,28,29)
                AT(6, 30,31,32,33) AT(7, 31,32,33,34) AT(8, 32,33,34,35)
            }
        }
        __syncthreads();
    }

    // dump all 8 partials, then 288 threads-worth of sums
    {
        float* rp = &red[t*9];                  // [ich][ocl][9]
        rp[0]=a0; rp[1]=a1; rp[2]=a2; rp[3]=a3; rp[4]=a4;
        rp[5]=a5; rp[6]=a6; rp[7]=a7; rp[8]=a8;
    }
    __syncthreads();
    for (int idx = t; idx < 288; idx += 256) {
        const int o2 = idx / 9, pos = idx % 9;
        float v = 0.f;
        #pragma unroll
        for (int k = 0; k < 8; k++) v += red[k*288 + idx];
        f_ws[n*577 + (oc0 + o2)*9 + pos] = LRELU(v);
    }

    // W1 transpose spread over blocks 0..7
    if (bid < 8) {
        for (int idx = t; idx < 2436; idx += 256) {
            const int g = bid*2436 + idx;       // 8*2436 = 609*32
            const int u = g & 31, a = g >> 5;
            W1T[g] = W1[u*609 + a];
        }
    }
}

// ---------------- Kernel B: M = F(512x577) @ T(577x512) -------------------
__global__ __launch_bounds__(256) void mgemm_kernel(
    const float* __restrict__ F,
    const float* __restrict__ T,
    float* __restrict__ M)
{
    const int rb = blockIdx.x >> 3;    // 64 row tiles of 8
    const int cb = blockIdx.x & 7;     // 8 col tiles of 64
    const int t = threadIdx.x;
    __shared__ float Fs[8*577];
    const int r0 = rb*8, c0 = cb*64;
    for (int r = 0; r < 8; r++)
        for (int a = t; a < 577; a += 256)
            Fs[r*577 + a] = F[(r0+r)*577 + a];
    __syncthreads();

    const int col = c0 + (t & 63);
    const int rg  = (t >> 6) * 2;      // wave-uniform
    const float* f0 = &Fs[rg*577];
    const float* f1 = &Fs[(rg+1)*577];
    float a0 = 0.f, a1 = 0.f;
    int a = 0;
    for (; a + 4 <= 577; a += 4) {
        float t0 = T[(a+0)*512 + col];
        float t1 = T[(a+1)*512 + col];
        float t2 = T[(a+2)*512 + col];
        float t3 = T[(a+3)*512 + col];
        a0 += f0[a]*t0 + f0[a+1]*t1 + f0[a+2]*t2 + f0[a+3]*t3;
        a1 += f1[a]*t0 + f1[a+1]*t1 + f1[a+2]*t2 + f1[a+3]*t3;
    }
    { // tail (a == 576)
        float tv = T[576*512 + col];
        a0 += f0[576]*tv;
        a1 += f1[576]*tv;
    }
    M[(r0+rg+0)*512 + col] = a0;
    M[(r0+rg+1)*512 + col] = a1;
}

// ---------------- Kernel C: o_part[isp][j][b] = sum_i exp(-L1) ------------
// grid 512: jt = bid>>5 (32 j's each), isp = bid&31 (16 i's each)
// 4 j's per thread -> 1 LDS b128 read per 32 pair-elements (broadcast floor)

#define LDM(R0, R1, R2, R3, JOFF) { \
    const float4* p_ = (const float4*)&M[(j0+jl+(JOFF))*512 + b*16]; \
    R0 = p_[0]; R1 = p_[1]; R2 = p_[2]; R3 = p_[3]; }

#define S16(P0, P1, P2, P3) \
  (fabsf(v0.x-P0.x)+fabsf(v0.y-P0.y)+fabsf(v0.z-P0.z)+fabsf(v0.w-P0.w) \
  +fabsf(v1.x-P1.x)+fabsf(v1.y-P1.y)+fabsf(v1.z-P1.z)+fabsf(v1.w-P1.w) \
  +fabsf(v2.x-P2.x)+fabsf(v2.y-P2.y)+fabsf(v2.z-P2.z)+fabsf(v2.w-P2.w) \
  +fabsf(v3.x-P3.x)+fabsf(v3.y-P3.y)+fabsf(v3.z-P3.z)+fabsf(v3.w-P3.w))

__global__ __launch_bounds__(256) void pairwise_kernel(
    const float* __restrict__ M,       // (512,512)
    float* __restrict__ o_part)        // (32,512,32)
{
    const int jt  = blockIdx.x >> 5;
    const int isp = blockIdx.x & 31;
    const int t = threadIdx.x;
    const int b = t & 31, jl = t >> 5;
    const int j0 = jt * 32;
    __shared__ float mi[16*572];       // padded: float off = x + ((x>>5)<<2)

    float4 mA0,mA1,mA2,mA3, mB0,mB1,mB2,mB3, mC0,mC1,mC2,mC3, mD0,mD1,mD2,mD3;
    LDM(mA0,mA1,mA2,mA3, 0)
    LDM(mB0,mB1,mB2,mB3, 8)
    LDM(mC0,mC1,mC2,mC3, 16)
    LDM(mD0,mD1,mD2,mD3, 24)

    // stage 16 i-rows
    const int i0 = isp * 16;
    #pragma unroll
    for (int k = 0; k < 8; k++) {
        const int q = k*256 + t;       // 0..2047
        const int r = q >> 7;
        const int x = (q & 127) * 4;
        float4 v = *(const float4*)&M[(i0+r)*512 + x];
        *(float4*)&mi[r*572 + x + ((x>>5)<<2)] = v;
    }
    __syncthreads();

    float acc0 = 0.f, acc1 = 0.f, acc2 = 0.f, acc3 = 0.f;
    const int lbase = b*16 + ((b>>1)<<2);

    #pragma unroll 4
    for (int r = 0; r < 16; r++) {
        const float4* q_ = (const float4*)&mi[r*572 + lbase];
        const float4 v0 = q_[0], v1 = q_[1], v2 = q_[2], v3 = q_[3];
        acc0 += __expf(-(S16(mA0,mA1,mA2,mA3)));
        acc1 += __expf(-(S16(mB0,mB1,mB2,mB3)));
        acc2 += __expf(-(S16(mC0,mC1,mC2,mC3)));
        acc3 += __expf(-(S16(mD0,mD1,mD2,mD3)));
    }
    const int ob = isp*16384 + b;
    o_part[ob + (j0+jl   )*32] = acc0;
    o_part[ob + (j0+jl+8 )*32] = acc1;
    o_part[ob + (j0+jl+16)*32] = acc2;
    o_part[ob + (j0+jl+24)*32] = acc3;
}

// ---------------- Kernel D: MLP head, one block per sample -----------------
__global__ __launch_bounds__(256) void mlp_kernel(
    const float* __restrict__ f,       // (512,577)
    const float* __restrict__ o_part,  // (32,512,32)
    const float* __restrict__ W1T,     // (609,32)
    const float* __restrict__ b1,      // (32)
    const float* __restrict__ W2,      // (1,32)
    const float* __restrict__ b2,      // (1)
    float* __restrict__ out)           // (512)
{
    const int j = blockIdx.x;
    const int t = threadIdx.x;
    __shared__ float xs[609];
    __shared__ float red[256];

    for (int a = t; a < 577; a += 256) xs[a] = f[j*577 + a];
    if (t < 32) {
        float ov = 0.f;
        #pragma unroll
        for (int isp = 0; isp < 32; isp++)
            ov += o_part[isp*16384 + j*32 + t];
        xs[577 + t] = ov;
    }
    __syncthreads();

    const int u = t & 31, seg = t >> 5;
    float p = 0.f;
    #pragma unroll 4
    for (int a = seg; a < 609; a += 8)
        p += xs[a] * W1T[a*32 + u];   // xs: LDS broadcast; W1T: coalesced 128B
    red[t] = p;
    __syncthreads();

    if (t < 32) {
        float hid = red[t];
        #pragma unroll
        for (int s = 1; s < 8; s++) hid += red[t + s*32];
        hid += b1[t];
        hid = LRELU(hid);
        float pr = hid * W2[t];
        #pragma unroll
        for (int mk = 16; mk; mk >>= 1) pr += __shfl_xor(pr, mk);
        if (t == 0) out[j] = 1.f / (1.f + __expf(-(pr + b2[0])));
    }
}

extern "C" void kernel_launch(void* const* d_in, const int* in_sizes, int n_in,
                              void* d_out, int out_size, void* d_ws, size_t ws_size,
                              hipStream_t stream) {
    const float* readout = (const float*)d_in[0];
    const float* energy  = (const float*)d_in[1];
    const float* w1      = (const float*)d_in[2];
    const float* w2      = (const float*)d_in[3];
    const float* T       = (const float*)d_in[4];
    const float* W1      = (const float*)d_in[5];
    const float* b1      = (const float*)d_in[6];
    const float* W2      = (const float*)d_in[7];
    const float* b2      = (const float*)d_in[8];
    float* out = (float*)d_out;

    char* ws = (char*)d_ws;
    float* f_ws   = (float*)(ws);                                       // 512*577 f32
    float* M_ws   = (float*)(ws + 512*577*4);                           // 512*512 f32
    float* o_ws   = (float*)(ws + 512*577*4 + 512*512*4);               // 32*512*32 f32
    float* W1T_ws = (float*)(ws + 512*577*4 + 512*512*4 + 32*512*32*4); // 609*32 f32

    convf_kernel   <<<1024, 256, 0, stream>>>(readout, energy, w1, w2, W1, f_ws, W1T_ws);
    mgemm_kernel   <<<512, 256, 0, stream>>>(f_ws, T, M_ws);
    pairwise_kernel<<<512, 256, 0, stream>>>(M_ws, o_ws);
    mlp_kernel     <<<512, 256, 0, stream>>>(f_ws, o_ws, W1T_ws, b1, W2, b2, out);
}

// Round 8
// 57.428 us; speedup vs baseline: 1.9656x; 1.0047x over previous
//
#include <hip/hip_runtime.h>

#define LRELU(v) ((v) >= 0.f ? (v) : 0.2f*(v))

// ---- conv1: named-register row access, all indices preprocessor literals --
#define ROROW(P, RB) \
    const float P##0=ro[(RB)+0], P##1=ro[(RB)+1], P##2=ro[(RB)+2], \
        P##3=ro[(RB)+3], P##4=ro[(RB)+4], P##5=ro[(RB)+5], \
        P##6=ro[(RB)+6], P##7=ro[(RB)+7], P##8=ro[(RB)+8];

#define C1X(X0,X1,X2,X3) \
    (wa.x*A##X0 + wa.y*A##X1 + wa.z*A##X2 + wa.w*A##X3 \
   + wb.x*B##X0 + wb.y*B##X1 + wb.z*B##X2 + wb.w*B##X3 \
   + wc.x*C##X0 + wc.y*C##X1 + wc.z*C##X2 + wc.w*C##X3 \
   + wd.x*D##X0 + wd.y*D##X1 + wd.z*D##X2 + wd.w*D##X3)

// ---- conv2: named-register h-row access: E<i> = element i of 36-float row -
#define E0 q0.x
#define E1 q0.y
#define E2 q0.z
#define E3 q0.w
#define E4 q1.x
#define E5 q1.y
#define E6 q1.z
#define E7 q1.w
#define E8 q2.x
#define E9 q2.y
#define E10 q2.z
#define E11 q2.w
#define E12 q3.x
#define E13 q3.y
#define E14 q3.z
#define E15 q3.w
#define E16 q4.x
#define E17 q4.y
#define E18 q4.z
#define E19 q4.w
#define E20 q5.x
#define E21 q5.y
#define E22 q5.z
#define E23 q5.w
#define E24 q6.x
#define E25 q6.y
#define E26 q6.z
#define E27 q6.w
#define E28 q7.x
#define E29 q7.y
#define E30 q7.z
#define E31 q7.w
#define E32 q8.x
#define E33 q8.y
#define E34 q8.z
#define E35 q8.w

#define AT(P, A, B, C, D) a##P += w.x*E##A + w.y*E##B + w.z*E##C + w.w*E##D;

// w2 chunk staging (32-oc slice), fully named regs (no arrays -> no scratch)
#define LD1(RK, K, BASE) { const int fidx_ = t + (K)*256; \
    const int woc_ = fidx_ >> 5, q4_ = fidx_ & 31; \
    RK = ((const float4*)w2)[(oc0 + woc_)*128 + (BASE) + q4_]; }
#define LDALL(BASE) LD1(r0,0,BASE) LD1(r1,1,BASE) LD1(r2,2,BASE) LD1(r3,3,BASE)
#define ST1(RK, K) { const int fidx_ = t + (K)*256; \
    const int woc_ = fidx_ >> 5, q4_ = fidx_ & 31; \
    *((float4*)&w2s[woc_*128 + ((q4_*4) ^ ((woc_ & 7) << 2))]) = RK; }
#define STALL ST1(r0,0) ST1(r1,1) ST1(r2,2) ST1(r3,3)

// ---------------- Kernel A: conv stack + f = [hidden(576), |sum(ro)-E|] ----
// Grid 1024: block = (sample n = bid>>1) x (oc-half och = bid&1).
__global__ __launch_bounds__(256) void convf_kernel(
    const float* __restrict__ readout,   // (512,1,9,9)
    const float* __restrict__ energy,    // (512)
    const float* __restrict__ w1,        // (32,1,4,4)
    const float* __restrict__ w2,        // (64,32,4,4)
    const float* __restrict__ W1,        // (32,609)
    float* __restrict__ f_ws,            // (512,577)
    float* __restrict__ W1T)             // (609,32)
{
    const int bid = blockIdx.x;
    const int n   = bid >> 1;
    const int och = bid & 1;
    const int oc0 = och << 5;            // 0 or 32 (w2 row base)
    const int t = threadIdx.x;
    __shared__ float ro[81];
    __shared__ float h1[1152];           // [ic(32)][pos(36)]
    __shared__ float w2s[4096];          // [ocl(32)][128] xor-swizzled chunk
    __shared__ float red[2304];          // [ich(8)][ocl(32)][9]

    if (t < 81) ro[t] = readout[n*81 + t];
    __syncthreads();

    // reco_energy (only och=0 blocks, wave 0)
    if (och == 0 && t < 64) {
        float v = ro[t];
        if (t < 17) v += ro[t + 64];
        #pragma unroll
        for (int m = 32; m; m >>= 1) v += __shfl_down(v, m);
        if (t == 0) f_ws[n*577 + 576] = fabsf(v - energy[n]);
    }

    // conv1: thread = (oc1 = t&31, y = t>>5), computes a full 6-wide row.
    // w1 row in 4 float4 regs (direct global), ro rows y..y+3 in 36 named regs.
    if (t < 192) {
        const int oc1 = t & 31, y = t >> 5;
        const float4* wp4 = (const float4*)&w1[oc1*16];
        const float4 wa = wp4[0], wb = wp4[1], wc = wp4[2], wd = wp4[3];
        const int rb0 = y*9;
        ROROW(A, rb0)
        ROROW(B, rb0+9)
        ROROW(C, rb0+18)
        ROROW(D, rb0+27)
        float* hp = &h1[oc1*36 + y*6];
        float v;
        v = C1X(0,1,2,3); hp[0] = LRELU(v);
        v = C1X(1,2,3,4); hp[1] = LRELU(v);
        v = C1X(2,3,4,5); hp[2] = LRELU(v);
        v = C1X(3,4,5,6); hp[3] = LRELU(v);
        v = C1X(4,5,6,7); hp[4] = LRELU(v);
        v = C1X(5,6,7,8); hp[5] = LRELU(v);
    }

    // prefetch w2 chunk 0 (coalesced float4, 4/thread)
    float4 r0, r1, r2, r3;
    LDALL(0)
    __syncthreads();                            // h1 ready

    const int ich = t >> 5, ocl = t & 31;
    float a0=0.f,a1=0.f,a2=0.f,a3=0.f,a4=0.f,a5=0.f,a6=0.f,a7=0.f,a8=0.f;
    const int wbase = ocl*128;
    const int wswz  = (ocl & 7) << 2;

    for (int chunk = 0; chunk < 4; chunk++) {
        STALL                                   // publish chunk to LDS (swizzled)
        __syncthreads();
        if (chunk < 3) { LDALL((chunk+1)*32) }  // prefetch next (hides L2 latency)

        {
            const int icw = ich;                // 1 ic per thread per chunk
            const int ic  = chunk*8 + ich;
            const float4* hp = (const float4*)&h1[ic*36];
            float4 q0=hp[0], q1=hp[1], q2=hp[2], q3=hp[3], q4=hp[4],
                   q5=hp[5], q6=hp[6], q7=hp[7], q8=hp[8];
            { // ky = 0
                float4 w = *((const float4*)&w2s[wbase + ((icw*16 + 0) ^ wswz)]);
                AT(0, 0,1,2,3)    AT(1, 1,2,3,4)    AT(2, 2,3,4,5)
                AT(3, 6,7,8,9)    AT(4, 7,8,9,10)   AT(5, 8,9,10,11)
                AT(6, 12,13,14,15) AT(7, 13,14,15,16) AT(8, 14,15,16,17)
            }
            { // ky = 1
                float4 w = *((const float4*)&w2s[wbase + ((icw*16 + 4) ^ wswz)]);
                AT(0, 6,7,8,9)    AT(1, 7,8,9,10)   AT(2, 8,9,10,11)
                AT(3, 12,13,14,15) AT(4, 13,14,15,16) AT(5, 14,15,16,17)
                AT(6, 18,19,20,21) AT(7, 19,20,21,22) AT(8, 20,21,22,23)
            }
            { // ky = 2
                float4 w = *((const float4*)&w2s[wbase + ((icw*16 + 8) ^ wswz)]);
                AT(0, 12,13,14,15) AT(1, 13,14,15,16) AT(2, 14,15,16,17)
                AT(3, 18,19,20,21) AT(4, 19,20,21,22) AT(5, 20,21,22,23)
                AT(6, 24,25,26,27) AT(7, 25,26,27,28) AT(8, 26,27,28,29)
            }
            { // ky = 3
                float4 w = *((const float4*)&w2s[wbase + ((icw*16 + 12) ^ wswz)]);
                AT(0, 18,19,20,21) AT(1, 19,20,21,22) AT(2, 20,21,22,23)
                AT(3, 24,25,26,27) AT(4, 25,26,27,28) AT(5, 26,27,28,29)
                AT(6, 30,31,32,33) AT(7, 31,32,33,34) AT(8, 32,33,34,35)
            }
        }
        __syncthreads();
    }

    // dump all 8 partials, then 288 threads-worth of sums
    {
        float* rp = &red[t*9];                  // [ich][ocl][9]
        rp[0]=a0; rp[1]=a1; rp[2]=a2; rp[3]=a3; rp[4]=a4;
        rp[5]=a5; rp[6]=a6; rp[7]=a7; rp[8]=a8;
    }
    __syncthreads();
    for (int idx = t; idx < 288; idx += 256) {
        const int o2 = idx / 9, pos = idx % 9;
        float v = 0.f;
        #pragma unroll
        for (int k = 0; k < 8; k++) v += red[k*288 + idx];
        f_ws[n*577 + (oc0 + o2)*9 + pos] = LRELU(v);
    }

    // W1 transpose spread over blocks 0..7
    if (bid < 8) {
        for (int idx = t; idx < 2436; idx += 256) {
            const int g = bid*2436 + idx;       // 8*2436 = 609*32
            const int u = g & 31, a = g >> 5;
            W1T[g] = W1[u*609 + a];
        }
    }
}

// ---------------- Kernel B: M = F(512x577) @ T(577x512) -------------------
// No LDS: F rows are wave-uniform -> readfirstlane forces the scalar path
// (s_load from K$/L2); T loads coalesced; inner loop = 8 FMA + 4 loads.
__global__ __launch_bounds__(256) void mgemm_kernel(
    const float* __restrict__ F,
    const float* __restrict__ T,
    float* __restrict__ M)
{
    const int rb = blockIdx.x >> 3;    // 64 row tiles of 8
    const int cb = blockIdx.x & 7;     // 8 col tiles of 64
    const int t = threadIdx.x;
    const int col = cb*64 + (t & 63);
    const int r0 = rb*8 + (t >> 6)*2;  // wave-uniform
    const int r0u = __builtin_amdgcn_readfirstlane(r0);
    const float* f0 = F + r0u*577;
    const float* f1 = f0 + 577;
    const float* Tc = T + col;
    float a0 = 0.f, a1 = 0.f;
    #pragma unroll 4
    for (int a = 0; a < 576; a += 4) {
        const float t0 = Tc[(a+0)*512];
        const float t1 = Tc[(a+1)*512];
        const float t2 = Tc[(a+2)*512];
        const float t3 = Tc[(a+3)*512];
        a0 += f0[a]*t0 + f0[a+1]*t1 + f0[a+2]*t2 + f0[a+3]*t3;
        a1 += f1[a]*t0 + f1[a+1]*t1 + f1[a+2]*t2 + f1[a+3]*t3;
    }
    { // tail (a == 576)
        const float tv = Tc[576*512];
        a0 += f0[576]*tv;
        a1 += f1[576]*tv;
    }
    M[(r0+0)*512 + col] = a0;
    M[(r0+1)*512 + col] = a1;
}

// ---------------- Kernel C: o_part[isp][j][b] = sum_i exp(-L1) ------------
// grid 512: jt = bid>>5 (32 j's each), isp = bid&31 (16 i's each)
#define LDM(R0, R1, R2, R3, JOFF) { \
    const float4* p_ = (const float4*)&M[(j0+jl+(JOFF))*512 + b*16]; \
    R0 = p_[0]; R1 = p_[1]; R2 = p_[2]; R3 = p_[3]; }

#define S16(P0, P1, P2, P3) \
  (fabsf(v0.x-P0.x)+fabsf(v0.y-P0.y)+fabsf(v0.z-P0.z)+fabsf(v0.w-P0.w) \
  +fabsf(v1.x-P1.x)+fabsf(v1.y-P1.y)+fabsf(v1.z-P1.z)+fabsf(v1.w-P1.w) \
  +fabsf(v2.x-P2.x)+fabsf(v2.y-P2.y)+fabsf(v2.z-P2.z)+fabsf(v2.w-P2.w) \
  +fabsf(v3.x-P3.x)+fabsf(v3.y-P3.y)+fabsf(v3.z-P3.z)+fabsf(v3.w-P3.w))

__global__ __launch_bounds__(256) void pairwise_kernel(
    const float* __restrict__ M,       // (512,512)
    float* __restrict__ o_part)        // (32,512,32)
{
    const int jt  = blockIdx.x >> 5;
    const int isp = blockIdx.x & 31;
    const int t = threadIdx.x;
    const int b = t & 31, jl = t >> 5;
    const int j0 = jt * 32;
    __shared__ float mi[16*572];       // padded: float off = x + ((x>>5)<<2)

    float4 mA0,mA1,mA2,mA3, mB0,mB1,mB2,mB3, mC0,mC1,mC2,mC3, mD0,mD1,mD2,mD3;
    LDM(mA0,mA1,mA2,mA3, 0)
    LDM(mB0,mB1,mB2,mB3, 8)
    LDM(mC0,mC1,mC2,mC3, 16)
    LDM(mD0,mD1,mD2,mD3, 24)

    // stage 16 i-rows
    const int i0 = isp * 16;
    #pragma unroll
    for (int k = 0; k < 8; k++) {
        const int q = k*256 + t;       // 0..2047
        const int r = q >> 7;
        const int x = (q & 127) * 4;
        float4 v = *(const float4*)&M[(i0+r)*512 + x];
        *(float4*)&mi[r*572 + x + ((x>>5)<<2)] = v;
    }
    __syncthreads();

    float acc0 = 0.f, acc1 = 0.f, acc2 = 0.f, acc3 = 0.f;
    const int lbase = b*16 + ((b>>1)<<2);

    #pragma unroll 4
    for (int r = 0; r < 16; r++) {
        const float4* q_ = (const float4*)&mi[r*572 + lbase];
        const float4 v0 = q_[0], v1 = q_[1], v2 = q_[2], v3 = q_[3];
        acc0 += __expf(-(S16(mA0,mA1,mA2,mA3)));
        acc1 += __expf(-(S16(mB0,mB1,mB2,mB3)));
        acc2 += __expf(-(S16(mC0,mC1,mC2,mC3)));
        acc3 += __expf(-(S16(mD0,mD1,mD2,mD3)));
    }
    const int ob = isp*16384 + b;
    o_part[ob + (j0+jl   )*32] = acc0;
    o_part[ob + (j0+jl+8 )*32] = acc1;
    o_part[ob + (j0+jl+16)*32] = acc2;
    o_part[ob + (j0+jl+24)*32] = acc3;
}

// ---------------- Kernel D: MLP head, one block per sample -----------------
__global__ __launch_bounds__(256) void mlp_kernel(
    const float* __restrict__ f,       // (512,577)
    const float* __restrict__ o_part,  // (32,512,32)
    const float* __restrict__ W1T,     // (609,32)
    const float* __restrict__ b1,      // (32)
    const float* __restrict__ W2,      // (1,32)
    const float* __restrict__ b2,      // (1)
    float* __restrict__ out)           // (512)
{
    const int j = blockIdx.x;
    const int t = threadIdx.x;
    __shared__ float xs[609];
    __shared__ float red[256];

    for (int a = t; a < 577; a += 256) xs[a] = f[j*577 + a];
    { // o reduction parallel over all 256 threads: (g = t>>5) sums 4 isps
        const int bb = t & 31, g = t >> 5;
        float ov = 0.f;
        #pragma unroll
        for (int k = 0; k < 4; k++)
            ov += o_part[(g + 8*k)*16384 + j*32 + bb];
        red[t] = ov;
    }
    __syncthreads();
    if (t < 32) {
        float ov = 0.f;
        #pragma unroll
        for (int g = 0; g < 8; g++) ov += red[t + g*32];
        xs[577 + t] = ov;
    }
    __syncthreads();

    const int u = t & 31, seg = t >> 5;
    float p = 0.f;
    #pragma unroll 4
    for (int a = seg; a < 609; a += 8)
        p += xs[a] * W1T[a*32 + u];   // xs: LDS broadcast; W1T: coalesced 128B
    red[t] = p;
    __syncthreads();

    if (t < 32) {
        float hid = red[t];
        #pragma unroll
        for (int s = 1; s < 8; s++) hid += red[t + s*32];
        hid += b1[t];
        hid = LRELU(hid);
        float pr = hid * W2[t];
        #pragma unroll
        for (int mk = 16; mk; mk >>= 1) pr += __shfl_xor(pr, mk);
        if (t == 0) out[j] = 1.f / (1.f + __expf(-(pr + b2[0])));
    }
}

extern "C" void kernel_launch(void* const* d_in, const int* in_sizes, int n_in,
                              void* d_out, int out_size, void* d_ws, size_t ws_size,
                              hipStream_t stream) {
    const float* readout = (const float*)d_in[0];
    const float* energy  = (const float*)d_in[1];
    const float* w1      = (const float*)d_in[2];
    const float* w2      = (const float*)d_in[3];
    const float* T       = (const float*)d_in[4];
    const float* W1      = (const float*)d_in[5];
    const float* b1      = (const float*)d_in[6];
    const float* W2      = (const float*)d_in[7];
    const float* b2      = (const float*)d_in[8];
    float* out = (float*)d_out;

    char* ws = (char*)d_ws;
    float* f_ws   = (float*)(ws);                                       // 512*577 f32
    float* M_ws   = (float*)(ws + 512*577*4);                           // 512*512 f32
    float* o_ws   = (float*)(ws + 512*577*4 + 512*512*4);               // 32*512*32 f32
    float* W1T_ws = (float*)(ws + 512*577*4 + 512*512*4 + 32*512*32*4); // 609*32 f32

    convf_kernel   <<<1024, 256, 0, stream>>>(readout, energy, w1, w2, W1, f_ws, W1T_ws);
    mgemm_kernel   <<<512, 256, 0, stream>>>(f_ws, T, M_ws);
    pairwise_kernel<<<512, 256, 0, stream>>>(M_ws, o_ws);
    mlp_kernel     <<<512, 256, 0, stream>>>(f_ws, o_ws, W1T_ws, b1, W2, b2, out);
}